// Round 2
// baseline (1232.882 us; speedup 1.0000x reference)
//
#include <hip/hip_runtime.h>

#define NN 40000
#define EE 640000
#define DD 128
#define LL 5

// ---------------- h0 = atom_emb[x_ids] (written to d_out, fp32) ----------------
__global__ void k_init(const int* __restrict__ x_ids, const float* __restrict__ atom_emb,
                       float* __restrict__ h){
  int idx = blockIdx.x * 256 + threadIdx.x;      // grid covers exactly NN*DD
  int n = idx >> 7, d = idx & 127;
  h[idx] = atom_emb[x_ids[n] * DD + d];
}

// ---------------- CSR build over dst ----------------
__global__ void k_count(const int* __restrict__ ei, int* __restrict__ deg){
  int e = blockIdx.x * 256 + threadIdx.x;
  atomicAdd(&deg[ei[EE + e]], 1);
}

__global__ void k_scan(const int* __restrict__ deg, int* __restrict__ row_start,
                       int* __restrict__ cursor, int n){
  __shared__ int buf[1024];
  __shared__ int s_carry;
  int tid = threadIdx.x;
  if (tid == 0) s_carry = 0;
  __syncthreads();
  for (int base = 0; base < n; base += 1024){
    int i = base + tid;
    int v = (i < n) ? deg[i] : 0;
    buf[tid] = v;
    __syncthreads();
    for (int off = 1; off < 1024; off <<= 1){
      int t = (tid >= off) ? buf[tid - off] : 0;
      __syncthreads();
      buf[tid] += t;
      __syncthreads();
    }
    int incl = buf[tid];
    int carry = s_carry;
    if (i < n){ int e = carry + incl - v; row_start[i] = e; cursor[i] = e; }
    __syncthreads();
    if (tid == 1023) s_carry = carry + incl;
    __syncthreads();
  }
  if (tid == 0) row_start[n] = s_carry;
}

__global__ void k_fill(const int* __restrict__ ei, const int* __restrict__ ea,
                       int* __restrict__ cursor, int* __restrict__ col){
  int e = blockIdx.x * 256 + threadIdx.x;
  int d = ei[EE + e];
  int pos = atomicAdd(&cursor[d], 1);
  col[pos] = ei[e] | (ea[e] << 20);   // src < 2^16, attr < 4
}

// ---------------- gather: z = (1+eps)*h + sum_in relu(h[src] + bond[attr]) ----------------
__global__ void k_gather(const float* __restrict__ h,
                         const int* __restrict__ row_start, const int* __restrict__ col,
                         const float* __restrict__ bond_l, const float* __restrict__ eps_l,
                         float* __restrict__ z){
  __shared__ float s_bond[4 * DD];
  __shared__ float s_eps;
  int tid = threadIdx.x;
  for (int i = tid; i < 4 * DD; i += 256) s_bond[i] = bond_l[i];
  if (tid == 0) s_eps = 1.0f + eps_l[0];
  __syncthreads();
  int wid = tid >> 6, lane = tid & 63;
  int v = blockIdx.x * 4 + wid;                   // NN divisible by 4
  int sbeg = row_start[v], send = row_start[v + 1];
  float a0 = 0.f, a1 = 0.f;
  const float2* h2 = (const float2*)h;
  for (int i = sbeg; i < send; ++i){
    int p = col[i];
    int u = p & 0xFFFFF;
    int a = p >> 20;
    float2 hv = h2[u * 64 + lane];                // 2 features per lane
    float2 bb = ((const float2*)(s_bond + a * DD))[lane];
    a0 += fmaxf(hv.x + bb.x, 0.f);
    a1 += fmaxf(hv.y + bb.y, 0.f);
  }
  float2 hv = h2[v * 64 + lane];
  float2 zr; zr.x = s_eps * hv.x + a0; zr.y = s_eps * hv.y + a1;
  ((float2*)z)[v * 64 + lane] = zr;
}

// ---------------- GEMM (+bias) with optional fused BN+ReLU on input; fused column stats out ----------------
template<bool BN>
__global__ __launch_bounds__(256) void k_gemm(const float* __restrict__ A,
    const float* __restrict__ W, const float* __restrict__ bias,
    const float* __restrict__ stats_in, const float* __restrict__ g, const float* __restrict__ bt,
    float* __restrict__ out, float* __restrict__ osum){
  __shared__ float sA[32 * DD];          // 16 KB
  __shared__ float s_scale[DD], s_shift[DD];
  __shared__ float s_sum[DD], s_sq[DD];
  int tid = threadIdx.x;
  int row0 = blockIdx.x * 32;            // NN/32 = 1250 blocks, exact
  if (tid < DD){
    s_sum[tid] = 0.f; s_sq[tid] = 0.f;
    if (BN){
      float m   = stats_in[tid] * (1.0f / NN);
      float var = stats_in[DD + tid] * (1.0f / NN) - m * m;
      float inv = rsqrtf(var + 1e-5f);
      float sc  = inv * g[tid];
      s_scale[tid] = sc;
      s_shift[tid] = bt[tid] - m * sc;
    }
  }
  __syncthreads();
  const float4* A4 = (const float4*)(A + row0 * DD);
  float4* sA4w = (float4*)sA;
  for (int i = tid; i < 32 * DD / 4; i += 256){
    float4 vv = A4[i];
    if (BN){
      int c = (i & 31) * 4;
      vv.x = fmaxf(vv.x * s_scale[c+0] + s_shift[c+0], 0.f);
      vv.y = fmaxf(vv.y * s_scale[c+1] + s_shift[c+1], 0.f);
      vv.z = fmaxf(vv.z * s_scale[c+2] + s_shift[c+2], 0.f);
      vv.w = fmaxf(vv.w * s_scale[c+3] + s_shift[c+3], 0.f);
    }
    sA4w[i] = vv;
  }
  __syncthreads();
  int jc = (tid & 31) * 4;
  int r0 = (tid >> 5) * 4;
  float acc[4][4];
  #pragma unroll
  for (int r = 0; r < 4; ++r)
    #pragma unroll
    for (int c = 0; c < 4; ++c) acc[r][c] = 0.f;
  const float4* sA4 = (const float4*)sA;
  const float4* Wv = (const float4*)W;
  for (int k4 = 0; k4 < 32; ++k4){
    float za[4][4];
    #pragma unroll
    for (int r = 0; r < 4; ++r){
      float4 t = sA4[(r0 + r) * 32 + k4];
      za[r][0] = t.x; za[r][1] = t.y; za[r][2] = t.z; za[r][3] = t.w;
    }
    #pragma unroll
    for (int i = 0; i < 4; ++i){
      float4 wr = Wv[((k4 * 4 + i) * DD + jc) >> 2];
      #pragma unroll
      for (int r = 0; r < 4; ++r){
        float av = za[r][i];
        acc[r][0] += av * wr.x; acc[r][1] += av * wr.y;
        acc[r][2] += av * wr.z; acc[r][3] += av * wr.w;
      }
    }
  }
  float4 br = ((const float4*)bias)[jc >> 2];
  float cs0=0,cs1=0,cs2=0,cs3=0, cq0=0,cq1=0,cq2=0,cq3=0;
  #pragma unroll
  for (int r = 0; r < 4; ++r){
    float y0 = acc[r][0] + br.x, y1 = acc[r][1] + br.y;
    float y2 = acc[r][2] + br.z, y3 = acc[r][3] + br.w;
    float4 ov; ov.x = y0; ov.y = y1; ov.z = y2; ov.w = y3;
    *(float4*)(out + (row0 + r0 + r) * DD + jc) = ov;
    cs0 += y0; cs1 += y1; cs2 += y2; cs3 += y3;
    cq0 += y0*y0; cq1 += y1*y1; cq2 += y2*y2; cq3 += y3*y3;
  }
  atomicAdd(&s_sum[jc+0], cs0); atomicAdd(&s_sum[jc+1], cs1);
  atomicAdd(&s_sum[jc+2], cs2); atomicAdd(&s_sum[jc+3], cs3);
  atomicAdd(&s_sq [jc+0], cq0); atomicAdd(&s_sq [jc+1], cq1);
  atomicAdd(&s_sq [jc+2], cq2); atomicAdd(&s_sq [jc+3], cq3);
  __syncthreads();
  if (tid < DD){
    atomicAdd(&osum[tid],      s_sum[tid]);
    atomicAdd(&osum[DD + tid], s_sq[tid]);
  }
}

// ---------------- BN2 (+ReLU except last) + residual into h (d_out) ----------------
__global__ void k_final(const float* __restrict__ w, const float* __restrict__ stats2,
                        const float* __restrict__ gl, const float* __restrict__ bl,
                        float* __restrict__ h, int do_relu){
  int idx = blockIdx.x * 256 + threadIdx.x;
  int j = idx & 127;
  float m   = stats2[j] * (1.0f / NN);
  float var = stats2[DD + j] * (1.0f / NN) - m * m;
  float inv = rsqrtf(var + 1e-5f);
  float val = (w[idx] - m) * inv * gl[j] + bl[j];
  if (do_relu) val = fmaxf(val, 0.f);
  h[idx] = h[idx] + val;
}

extern "C" void kernel_launch(void* const* d_in, const int* in_sizes, int n_in,
                              void* d_out, int out_size, void* d_ws, size_t ws_size,
                              hipStream_t stream) {
  const int*   x_ids      = (const int*)d_in[0];
  const int*   edge_index = (const int*)d_in[1];
  const int*   edge_attr  = (const int*)d_in[2];
  const float* atom_emb   = (const float*)d_in[3];
  const float* bond_emb   = (const float*)d_in[4];
  const float* W1    = (const float*)d_in[5];
  const float* b1    = (const float*)d_in[6];
  const float* g1    = (const float*)d_in[7];
  const float* bt1   = (const float*)d_in[8];
  const float* W2    = (const float*)d_in[9];
  const float* b2    = (const float*)d_in[10];
  const float* eps   = (const float*)d_in[11];
  const float* g_out = (const float*)d_in[12];
  const float* b_out = (const float*)d_in[13];

  float* h  = (float*)d_out;                // NN*DD fp32 — running node state, final output
  float* z1 = (float*)d_ws;                 // NN*DD fp32
  float* z2 = z1 + NN * DD;                 // NN*DD fp32
  float* stats = z2 + NN * DD;              // 512 fp32: [sum1|sq1|sum2|sq2]
  int* row_start = (int*)(stats + 512);     // NN+1 (padded)
  int* cursor    = row_start + NN + 4;      // NN
  int* deg       = cursor + NN;             // NN
  int* col       = deg + NN;                // EE

  hipMemsetAsync(deg, 0, NN * sizeof(int), stream);
  k_init <<<NN * DD / 256, 256, 0, stream>>>(x_ids, atom_emb, h);
  k_count<<<EE / 256, 256, 0, stream>>>(edge_index, deg);
  k_scan <<<1, 1024, 0, stream>>>(deg, row_start, cursor, NN);
  k_fill <<<EE / 256, 256, 0, stream>>>(edge_index, edge_attr, cursor, col);

  for (int l = 0; l < LL; ++l){
    hipMemsetAsync(stats, 0, 512 * sizeof(float), stream);
    k_gather<<<NN / 4, 256, 0, stream>>>(h, row_start, col,
                                         bond_emb + l * 4 * DD, eps + l, z1);
    k_gemm<false><<<NN / 32, 256, 0, stream>>>(z1, W1 + l * DD * DD, b1 + l * DD,
                                               nullptr, nullptr, nullptr, z2, stats);
    k_gemm<true> <<<NN / 32, 256, 0, stream>>>(z2, W2 + l * DD * DD, b2 + l * DD,
                                               stats, g1 + l * DD, bt1 + l * DD, z1, stats + 2 * DD);
    k_final<<<NN * DD / 256, 256, 0, stream>>>(z1, stats + 2 * DD,
                                               g_out + l * DD, b_out + l * DD,
                                               h, (l < LL - 1) ? 1 : 0);
  }
}

// Round 3
// 930.259 us; speedup vs baseline: 1.3253x; 1.3253x over previous
//
#include <hip/hip_runtime.h>

#define NN 40000
#define EE 640000
#define DD 128
#define LL 5

typedef unsigned short u16;
typedef unsigned int   u32;
typedef __attribute__((ext_vector_type(8))) short bf8;   // 8 bf16 = 4 VGPRs
typedef __attribute__((ext_vector_type(4))) float f4;

__device__ __forceinline__ float bf2f(u32 u){ union{u32 i; float f;} x; x.i = u << 16; return x.f; }
__device__ __forceinline__ u16 f2bf(float f){
  union{float f; u32 i;} x; x.f = f;
  u32 r = x.i + 0x7FFFu + ((x.i >> 16) & 1u);
  return (u16)(r >> 16);
}
__device__ __forceinline__ u32 pack2(float a, float b){ return (u32)f2bf(a) | ((u32)f2bf(b) << 16); }

// ---------------- h0 = atom_emb[x_ids]: fp32 h (d_out) + bf16 mirror ----------------
__global__ void k_init(const int* __restrict__ x_ids, const float* __restrict__ atom_emb,
                       float* __restrict__ h, u32* __restrict__ hb){
  int idx = blockIdx.x * 256 + threadIdx.x;      // NN*64 (2 feats/thread)
  int n = idx >> 6, d2 = idx & 63;
  float2 v = ((const float2*)(atom_emb + x_ids[n] * DD))[d2];
  ((float2*)h)[idx] = v;
  hb[idx] = pack2(v.x, v.y);
}

// ---------------- transpose+cast weights: wt[m][n][k] = bf16(W_m[k][n]) ----------------
__global__ void k_wprep(const float* __restrict__ W1, const float* __restrict__ W2,
                        u16* __restrict__ wt){
  int idx = blockIdx.x * 256 + threadIdx.x;      // 10*16384
  int m = idx >> 14, nk = idx & 16383;
  int n = nk >> 7, k = nk & 127;
  const float* src = (m < LL) ? (W1 + m * 16384) : (W2 + (m - LL) * 16384);
  wt[idx] = f2bf(src[k * DD + n]);
}

// ---------------- CSR build over dst ----------------
__global__ void k_count(const int* __restrict__ ei, int* __restrict__ deg){
  int e = blockIdx.x * 256 + threadIdx.x;
  atomicAdd(&deg[ei[EE + e]], 1);
}

__global__ void k_scan(const int* __restrict__ deg, int* __restrict__ row_start,
                       int* __restrict__ cursor, int n){
  __shared__ int buf[1024];
  __shared__ int s_carry;
  int tid = threadIdx.x;
  if (tid == 0) s_carry = 0;
  __syncthreads();
  for (int base = 0; base < n; base += 1024){
    int i = base + tid;
    int v = (i < n) ? deg[i] : 0;
    buf[tid] = v;
    __syncthreads();
    for (int off = 1; off < 1024; off <<= 1){
      int t = (tid >= off) ? buf[tid - off] : 0;
      __syncthreads();
      buf[tid] += t;
      __syncthreads();
    }
    int incl = buf[tid];
    int carry = s_carry;
    if (i < n){ int e = carry + incl - v; row_start[i] = e; cursor[i] = e; }
    __syncthreads();
    if (tid == 1023) s_carry = carry + incl;
    __syncthreads();
  }
  if (tid == 0) row_start[n] = s_carry;
}

__global__ void k_fill(const int* __restrict__ ei, const int* __restrict__ ea,
                       int* __restrict__ cursor, int* __restrict__ col){
  int e = blockIdx.x * 256 + threadIdx.x;
  int d = ei[EE + e];
  int pos = atomicAdd(&cursor[d], 1);
  col[pos] = ei[e] | (ea[e] << 20);   // src < 2^17, attr < 4
}

// ---------------- gather: zb = bf16( (1+eps)*h + sum relu(hb[src]+bond[attr]) ) ----------------
__global__ void k_gather(const float* __restrict__ h, const u32* __restrict__ hb,
                         const int* __restrict__ row_start, const int* __restrict__ col,
                         const float* __restrict__ bond_l, const float* __restrict__ eps_l,
                         u32* __restrict__ zb){
  __shared__ float2 s_bond[4 * 64];
  __shared__ float s_eps;
  int tid = threadIdx.x;
  if (tid < 256) s_bond[tid] = ((const float2*)bond_l)[tid];
  if (tid == 0) s_eps = 1.0f + eps_l[0];
  __syncthreads();
  int wid = tid >> 6, lane = tid & 63;
  int v = blockIdx.x * 4 + wid;                   // NN divisible by 4
  int sbeg = row_start[v], send = row_start[v + 1];
  float a0 = 0.f, a1 = 0.f, c0 = 0.f, c1 = 0.f;
  int i = sbeg;
  for (; i + 2 <= send; i += 2){
    int p0 = col[i], p1 = col[i + 1];
    u32 h0 = hb[(p0 & 0xFFFFF) * 64 + lane];
    u32 h1 = hb[(p1 & 0xFFFFF) * 64 + lane];
    float2 bb0 = s_bond[(p0 >> 20) * 64 + lane];
    float2 bb1 = s_bond[(p1 >> 20) * 64 + lane];
    a0 += fmaxf(bf2f(h0 & 0xFFFFu) + bb0.x, 0.f);
    a1 += fmaxf(bf2f(h0 >> 16)     + bb0.y, 0.f);
    c0 += fmaxf(bf2f(h1 & 0xFFFFu) + bb1.x, 0.f);
    c1 += fmaxf(bf2f(h1 >> 16)     + bb1.y, 0.f);
  }
  if (i < send){
    int p0 = col[i];
    u32 h0 = hb[(p0 & 0xFFFFF) * 64 + lane];
    float2 bb0 = s_bond[(p0 >> 20) * 64 + lane];
    a0 += fmaxf(bf2f(h0 & 0xFFFFu) + bb0.x, 0.f);
    a1 += fmaxf(bf2f(h0 >> 16)     + bb0.y, 0.f);
  }
  float2 hv = ((const float2*)h)[v * 64 + lane];
  zb[v * 64 + lane] = pack2(s_eps * hv.x + a0 + c0, s_eps * hv.y + a1 + c1);
}

// ---------------- MFMA GEMM: out = A @ W + b, fused col stats; BN+ReLU on input if BN ----------------
// A: 32 rows/block. !BN: Asrc is bf16 [NN][128]. BN: Asrc is fp32, transform then cast.
template<bool BN>
__global__ __launch_bounds__(256) void k_gemm(const void* __restrict__ Asrc,
    const u16* __restrict__ Wt,               // bf16 Wt[n][k]
    const float* __restrict__ bias,
    const float* __restrict__ stats_in, const float* __restrict__ g, const float* __restrict__ bt,
    float* __restrict__ out, float* __restrict__ osum){
  __shared__ u16 sA[32 * 136];                // padded rows: 272 B = 68 dw -> 2-way banks (free)
  __shared__ float s_scale[DD], s_shift[DD];
  __shared__ float s_sum[DD], s_sq[DD];
  int tid = threadIdx.x;
  int row0 = blockIdx.x * 32;                 // 1250 blocks exact
  if (tid < DD){
    s_sum[tid] = 0.f; s_sq[tid] = 0.f;
    if (BN){
      float m   = stats_in[tid] * (1.0f / NN);
      float var = stats_in[DD + tid] * (1.0f / NN) - m * m;
      float inv = rsqrtf(var + 1e-5f);
      float sc  = inv * g[tid];
      s_scale[tid] = sc;
      s_shift[tid] = bt[tid] - m * sc;
    }
  }
  __syncthreads();
  // stage A tile: 32x128 bf16, 2 chunks of 8 elems per thread
  #pragma unroll
  for (int c0 = 0; c0 < 2; ++c0){
    int c = tid + c0 * 256;
    int row = c >> 4, off = (c & 15) * 8;
    if (!BN){
      uint4 v = *(const uint4*)((const u16*)Asrc + (row0 + row) * DD + off);
      *(uint4*)(sA + row * 136 + off) = v;
    } else {
      const float* src = (const float*)Asrc + (row0 + row) * DD + off;
      float4 v0 = *(const float4*)src;
      float4 v1 = *(const float4*)(src + 4);
      float y[8] = {v0.x, v0.y, v0.z, v0.w, v1.x, v1.y, v1.z, v1.w};
      union { u16 o[8]; uint4 v; } u;
      #pragma unroll
      for (int j = 0; j < 8; ++j)
        u.o[j] = f2bf(fmaxf(y[j] * s_scale[off + j] + s_shift[off + j], 0.f));
      *(uint4*)(sA + row * 136 + off) = u.v;
    }
  }
  // preload B fragments straight from global (L2-resident Wt)
  int w = tid >> 6, lane = tid & 63, lr = lane & 15, lk = lane >> 4;
  bf8 bfr[2][4];
  #pragma unroll
  for (int nt = 0; nt < 2; ++nt){
    int n = w * 32 + nt * 16 + lr;
    #pragma unroll
    for (int kt = 0; kt < 4; ++kt)
      bfr[nt][kt] = *(const bf8*)(Wt + n * DD + kt * 32 + lk * 8);
  }
  __syncthreads();
  f4 acc[2][2];
  #pragma unroll
  for (int mt = 0; mt < 2; ++mt)
    #pragma unroll
    for (int nt = 0; nt < 2; ++nt) acc[mt][nt] = (f4){0.f, 0.f, 0.f, 0.f};
  #pragma unroll
  for (int kt = 0; kt < 4; ++kt){
    bf8 a0 = *(const bf8*)(sA + lr * 136        + kt * 32 + lk * 8);
    bf8 a1 = *(const bf8*)(sA + (16 + lr) * 136 + kt * 32 + lk * 8);
    acc[0][0] = __builtin_amdgcn_mfma_f32_16x16x32_bf16(a0, bfr[0][kt], acc[0][0], 0, 0, 0);
    acc[0][1] = __builtin_amdgcn_mfma_f32_16x16x32_bf16(a0, bfr[1][kt], acc[0][1], 0, 0, 0);
    acc[1][0] = __builtin_amdgcn_mfma_f32_16x16x32_bf16(a1, bfr[0][kt], acc[1][0], 0, 0, 0);
    acc[1][1] = __builtin_amdgcn_mfma_f32_16x16x32_bf16(a1, bfr[1][kt], acc[1][1], 0, 0, 0);
  }
  // epilogue: C/D layout col=lane&15, row=(lane>>4)*4+reg
  #pragma unroll
  for (int nt = 0; nt < 2; ++nt){
    int colg = w * 32 + nt * 16 + lr;
    float bv = bias[colg];
    float cs = 0.f, cq = 0.f;
    #pragma unroll
    for (int mt = 0; mt < 2; ++mt){
      #pragma unroll
      for (int r = 0; r < 4; ++r){
        float y = acc[mt][nt][r] + bv;
        out[(row0 + mt * 16 + lk * 4 + r) * DD + colg] = y;
        cs += y; cq += y * y;
      }
    }
    atomicAdd(&s_sum[colg], cs);
    atomicAdd(&s_sq[colg], cq);
  }
  __syncthreads();
  if (tid < DD){
    atomicAdd(&osum[tid],      s_sum[tid]);
    atomicAdd(&osum[DD + tid], s_sq[tid]);
  }
}

// ---------------- BN2 (+ReLU except last) + residual; update fp32 h and bf16 mirror ----------------
__global__ void k_final(const float* __restrict__ zf, const float* __restrict__ stats2,
                        const float* __restrict__ gl, const float* __restrict__ bl,
                        float* __restrict__ h, u32* __restrict__ hb, int do_relu){
  int idx = blockIdx.x * 256 + threadIdx.x;   // NN*64
  int j0 = (idx & 63) * 2;
  float2 zz = ((const float2*)zf)[idx];
  float m0 = stats2[j0] * (1.0f / NN),     m1 = stats2[j0 + 1] * (1.0f / NN);
  float v0 = stats2[DD + j0] * (1.0f / NN) - m0 * m0;
  float v1 = stats2[DD + j0 + 1] * (1.0f / NN) - m1 * m1;
  float val0 = (zz.x - m0) * rsqrtf(v0 + 1e-5f) * gl[j0]     + bl[j0];
  float val1 = (zz.y - m1) * rsqrtf(v1 + 1e-5f) * gl[j0 + 1] + bl[j0 + 1];
  if (do_relu){ val0 = fmaxf(val0, 0.f); val1 = fmaxf(val1, 0.f); }
  float2 hv = ((float2*)h)[idx];
  hv.x += val0; hv.y += val1;
  ((float2*)h)[idx] = hv;
  hb[idx] = pack2(hv.x, hv.y);
}

extern "C" void kernel_launch(void* const* d_in, const int* in_sizes, int n_in,
                              void* d_out, int out_size, void* d_ws, size_t ws_size,
                              hipStream_t stream) {
  const int*   x_ids      = (const int*)d_in[0];
  const int*   edge_index = (const int*)d_in[1];
  const int*   edge_attr  = (const int*)d_in[2];
  const float* atom_emb   = (const float*)d_in[3];
  const float* bond_emb   = (const float*)d_in[4];
  const float* W1    = (const float*)d_in[5];
  const float* b1    = (const float*)d_in[6];
  const float* g1    = (const float*)d_in[7];
  const float* bt1   = (const float*)d_in[8];
  const float* W2    = (const float*)d_in[9];
  const float* b2    = (const float*)d_in[10];
  const float* eps   = (const float*)d_in[11];
  const float* g_out = (const float*)d_in[12];
  const float* b_out = (const float*)d_in[13];

  float* h  = (float*)d_out;                 // NN*DD fp32 running node state
  float* zA = (float*)d_ws;                  // NN*DD fp32 (GEMM2 out); first half doubles as bf16 z (gather out)
  float* z2 = zA + NN * DD;                  // NN*DD fp32 (GEMM1 out)
  u32*   hb = (u32*)(z2 + NN * DD);          // NN*64: bf16 mirror of h
  u16*   wt = (u16*)(hb + NN * 64);          // 10*16384 bf16 transposed weights
  float* stats = (float*)(wt + 10 * 16384);  // 512: [sum1|sq1|sum2|sq2]
  int* row_start = (int*)(stats + 512);      // NN+1 (padded)
  int* cursor    = row_start + NN + 4;
  int* deg       = cursor + NN;
  int* col       = deg + NN;                 // EE

  u32* zb = (u32*)zA;                        // bf16 gather output, aliases zA (disjoint lifetime)

  hipMemsetAsync(deg, 0, NN * sizeof(int), stream);
  k_init <<<NN * 64 / 256, 256, 0, stream>>>(x_ids, atom_emb, h, hb);
  k_wprep<<<10 * 16384 / 256, 256, 0, stream>>>(W1, W2, wt);
  k_count<<<EE / 256, 256, 0, stream>>>(edge_index, deg);
  k_scan <<<1, 1024, 0, stream>>>(deg, row_start, cursor, NN);
  k_fill <<<EE / 256, 256, 0, stream>>>(edge_index, edge_attr, cursor, col);

  for (int l = 0; l < LL; ++l){
    hipMemsetAsync(stats, 0, 512 * sizeof(float), stream);
    k_gather<<<NN / 4, 256, 0, stream>>>(h, hb, row_start, col,
                                         bond_emb + l * 4 * DD, eps + l, zb);
    k_gemm<false><<<NN / 32, 256, 0, stream>>>(zb, wt + l * 16384, b1 + l * DD,
                                               nullptr, nullptr, nullptr, z2, stats);
    k_gemm<true> <<<NN / 32, 256, 0, stream>>>(z2, wt + (LL + l) * 16384, b2 + l * DD,
                                               stats, g1 + l * DD, bt1 + l * DD, zA, stats + 2 * DD);
    k_final<<<NN * 64 / 256, 256, 0, stream>>>(zA, stats + 2 * DD,
                                               g_out + l * DD, b_out + l * DD,
                                               h, hb, (l < LL - 1) ? 1 : 0);
  }
}

// Round 4
// 777.697 us; speedup vs baseline: 1.5853x; 1.1962x over previous
//
#include <hip/hip_runtime.h>

#define NN 40000
#define EE 640000
#define DD 128
#define LL 5

typedef unsigned short u16;
typedef unsigned int   u32;
typedef __attribute__((ext_vector_type(8))) short bf8;   // 8 bf16 = 4 VGPRs
typedef __attribute__((ext_vector_type(4))) float f4;

__device__ __forceinline__ float bf2f(u32 u){ union{u32 i; float f;} x; x.i = u << 16; return x.f; }
__device__ __forceinline__ u16 f2bf(float f){
  union{float f; u32 i;} x; x.f = f;
  u32 r = x.i + 0x7FFFu + ((x.i >> 16) & 1u);
  return (u16)(r >> 16);
}
__device__ __forceinline__ u32 pack2(float a, float b){ return (u32)f2bf(a) | ((u32)f2bf(b) << 16); }

// ---------------- h0 = atom_emb[x_ids]: fp32 h (d_out) + bf16 mirror; also zero deg ----------------
__global__ void k_init(const int* __restrict__ x_ids, const float* __restrict__ atom_emb,
                       float* __restrict__ h, u32* __restrict__ hb, int* __restrict__ deg){
  int idx = blockIdx.x * 256 + threadIdx.x;      // NN*64 (2 feats/thread)
  if (idx < NN) deg[idx] = 0;
  int n = idx >> 6, d2 = idx & 63;
  float2 v = ((const float2*)(atom_emb + x_ids[n] * DD))[d2];
  ((float2*)h)[idx] = v;
  hb[idx] = pack2(v.x, v.y);
}

// ---------------- transpose+cast weights: wt[m][n][k] = bf16(W_m[k][n]) ----------------
__global__ void k_wprep(const float* __restrict__ W1, const float* __restrict__ W2,
                        u16* __restrict__ wt){
  int idx = blockIdx.x * 256 + threadIdx.x;      // 10*16384
  int m = idx >> 14, nk = idx & 16383;
  int n = nk >> 7, k = nk & 127;
  const float* src = (m < LL) ? (W1 + m * 16384) : (W2 + (m - LL) * 16384);
  wt[idx] = f2bf(src[k * DD + n]);
}

// ---------------- CSR build over dst ----------------
__global__ void k_count(const int* __restrict__ ei, int* __restrict__ deg){
  int e = blockIdx.x * 256 + threadIdx.x;
  atomicAdd(&deg[ei[EE + e]], 1);
}

// multi-block scan, phase 1: per-block exclusive scan + block totals (40 blocks x 1024)
__global__ void k_scan1(const int* __restrict__ deg, int* __restrict__ rs, int* __restrict__ bsum){
  __shared__ int buf[1024];
  int tid = threadIdx.x;
  int i = blockIdx.x * 1024 + tid;
  int v = (i < NN) ? deg[i] : 0;
  buf[tid] = v;
  __syncthreads();
  for (int off = 1; off < 1024; off <<= 1){
    int t = (tid >= off) ? buf[tid - off] : 0;
    __syncthreads();
    buf[tid] += t;
    __syncthreads();
  }
  int incl = buf[tid];
  if (i < NN) rs[i] = incl - v;                  // block-local exclusive
  if (tid == 1023) bsum[blockIdx.x] = incl;
}

// phase 2: add scanned block offsets, write cursor, set rs[NN]=EE
__global__ void k_scan2(int* __restrict__ rs, const int* __restrict__ bsum, int* __restrict__ cursor){
  __shared__ int s_off;
  int tid = threadIdx.x;
  if (tid < 64){
    int v = (tid < 40) ? bsum[tid] : 0;
    #pragma unroll
    for (int off = 1; off < 64; off <<= 1){
      int t = __shfl_up(v, off, 64);
      if (tid >= off) v += t;
    }
    int bx = (int)blockIdx.x;
    int ex = (bx == 0) ? 0 : __shfl(v, bx - 1, 64);
    if (tid == 0) s_off = ex;
  }
  __syncthreads();
  int i = blockIdx.x * 1024 + tid;
  if (i < NN){
    int e = rs[i] + s_off;
    rs[i] = e;
    cursor[i] = e;
  }
  if (i == 0) rs[NN] = EE;
}

__global__ void k_fill(const int* __restrict__ ei, const int* __restrict__ ea,
                       int* __restrict__ cursor, int* __restrict__ col){
  int e = blockIdx.x * 256 + threadIdx.x;
  int d = ei[EE + e];
  int pos = atomicAdd(&cursor[d], 1);
  col[pos] = ei[e] | (ea[e] << 20);   // src < 2^17, attr < 4
}

// ---------------- gather: zb = bf16( (1+eps)*h + sum relu(hb[src]+bond[attr]) ); zeroes stats ----------------
__global__ void k_gather(const float* __restrict__ h, const u32* __restrict__ hb,
                         const int* __restrict__ row_start, const int* __restrict__ col,
                         const float* __restrict__ bond_l, const float* __restrict__ eps_l,
                         u32* __restrict__ zb, float* __restrict__ stats){
  __shared__ float2 s_bond[4 * 64];
  __shared__ float s_eps;
  int tid = threadIdx.x;
  if (blockIdx.x == 0){                           // stats zeroed before gemm1 launches (stream order)
    stats[tid] = 0.f; stats[256 + tid] = 0.f;
  }
  if (tid < 256) s_bond[tid] = ((const float2*)bond_l)[tid];
  if (tid == 0) s_eps = 1.0f + eps_l[0];
  __syncthreads();
  int wid = tid >> 6, lane = tid & 63;
  int v = blockIdx.x * 4 + wid;                   // NN divisible by 4
  int sbeg = __builtin_amdgcn_readfirstlane(row_start[v]);
  int send = __builtin_amdgcn_readfirstlane(row_start[v + 1]);
  float a0 = 0.f, a1 = 0.f, b0 = 0.f, b1 = 0.f, c0 = 0.f, c1 = 0.f, d0 = 0.f, d1 = 0.f;
  int i = sbeg;
  for (; i + 4 <= send; i += 4){
    int p0 = col[i], p1 = col[i + 1], p2 = col[i + 2], p3 = col[i + 3];
    u32 h0 = hb[(p0 & 0xFFFFF) * 64 + lane];
    u32 h1 = hb[(p1 & 0xFFFFF) * 64 + lane];
    u32 h2 = hb[(p2 & 0xFFFFF) * 64 + lane];
    u32 h3 = hb[(p3 & 0xFFFFF) * 64 + lane];
    float2 bb0 = s_bond[(p0 >> 20) * 64 + lane];
    float2 bb1 = s_bond[(p1 >> 20) * 64 + lane];
    float2 bb2 = s_bond[(p2 >> 20) * 64 + lane];
    float2 bb3 = s_bond[(p3 >> 20) * 64 + lane];
    a0 += fmaxf(bf2f(h0 & 0xFFFFu) + bb0.x, 0.f);
    a1 += fmaxf(bf2f(h0 >> 16)     + bb0.y, 0.f);
    b0 += fmaxf(bf2f(h1 & 0xFFFFu) + bb1.x, 0.f);
    b1 += fmaxf(bf2f(h1 >> 16)     + bb1.y, 0.f);
    c0 += fmaxf(bf2f(h2 & 0xFFFFu) + bb2.x, 0.f);
    c1 += fmaxf(bf2f(h2 >> 16)     + bb2.y, 0.f);
    d0 += fmaxf(bf2f(h3 & 0xFFFFu) + bb3.x, 0.f);
    d1 += fmaxf(bf2f(h3 >> 16)     + bb3.y, 0.f);
  }
  for (; i < send; ++i){
    int p0 = col[i];
    u32 h0 = hb[(p0 & 0xFFFFF) * 64 + lane];
    float2 bb0 = s_bond[(p0 >> 20) * 64 + lane];
    a0 += fmaxf(bf2f(h0 & 0xFFFFu) + bb0.x, 0.f);
    a1 += fmaxf(bf2f(h0 >> 16)     + bb0.y, 0.f);
  }
  float2 hv = ((const float2*)h)[v * 64 + lane];
  zb[v * 64 + lane] = pack2(s_eps * hv.x + a0 + b0 + c0 + d0,
                            s_eps * hv.y + a1 + b1 + c1 + d1);
}

// ---------------- MFMA GEMM: out = A @ W + b, fused col stats; BN+ReLU on input if BN ----------------
template<bool BN>
__global__ __launch_bounds__(256) void k_gemm(const void* __restrict__ Asrc,
    const u16* __restrict__ Wt,               // bf16 Wt[n][k]
    const float* __restrict__ bias,
    const float* __restrict__ stats_in, const float* __restrict__ g, const float* __restrict__ bt,
    float* __restrict__ out, float* __restrict__ osum){
  __shared__ u16 sA[32 * 136];                // padded rows: 2-way bank aliasing (free)
  __shared__ float s_scale[DD], s_shift[DD];
  __shared__ float s_sum[DD], s_sq[DD];
  int tid = threadIdx.x;
  int row0 = blockIdx.x * 32;                 // 1250 blocks exact
  if (tid < DD){
    s_sum[tid] = 0.f; s_sq[tid] = 0.f;
    if (BN){
      float m   = stats_in[tid] * (1.0f / NN);
      float var = stats_in[DD + tid] * (1.0f / NN) - m * m;
      float inv = rsqrtf(var + 1e-5f);
      float sc  = inv * g[tid];
      s_scale[tid] = sc;
      s_shift[tid] = bt[tid] - m * sc;
    }
  }
  __syncthreads();
  #pragma unroll
  for (int c0 = 0; c0 < 2; ++c0){
    int c = tid + c0 * 256;
    int row = c >> 4, off = (c & 15) * 8;
    if (!BN){
      uint4 v = *(const uint4*)((const u16*)Asrc + (row0 + row) * DD + off);
      *(uint4*)(sA + row * 136 + off) = v;
    } else {
      const float* src = (const float*)Asrc + (row0 + row) * DD + off;
      float4 v0 = *(const float4*)src;
      float4 v1 = *(const float4*)(src + 4);
      float y[8] = {v0.x, v0.y, v0.z, v0.w, v1.x, v1.y, v1.z, v1.w};
      union { u16 o[8]; uint4 v; } u;
      #pragma unroll
      for (int j = 0; j < 8; ++j)
        u.o[j] = f2bf(fmaxf(y[j] * s_scale[off + j] + s_shift[off + j], 0.f));
      *(uint4*)(sA + row * 136 + off) = u.v;
    }
  }
  int w = tid >> 6, lane = tid & 63, lr = lane & 15, lk = lane >> 4;
  bf8 bfr[2][4];
  #pragma unroll
  for (int nt = 0; nt < 2; ++nt){
    int n = w * 32 + nt * 16 + lr;
    #pragma unroll
    for (int kt = 0; kt < 4; ++kt)
      bfr[nt][kt] = *(const bf8*)(Wt + n * DD + kt * 32 + lk * 8);
  }
  __syncthreads();
  f4 acc[2][2];
  #pragma unroll
  for (int mt = 0; mt < 2; ++mt)
    #pragma unroll
    for (int nt = 0; nt < 2; ++nt) acc[mt][nt] = (f4){0.f, 0.f, 0.f, 0.f};
  #pragma unroll
  for (int kt = 0; kt < 4; ++kt){
    bf8 a0 = *(const bf8*)(sA + lr * 136        + kt * 32 + lk * 8);
    bf8 a1 = *(const bf8*)(sA + (16 + lr) * 136 + kt * 32 + lk * 8);
    acc[0][0] = __builtin_amdgcn_mfma_f32_16x16x32_bf16(a0, bfr[0][kt], acc[0][0], 0, 0, 0);
    acc[0][1] = __builtin_amdgcn_mfma_f32_16x16x32_bf16(a0, bfr[1][kt], acc[0][1], 0, 0, 0);
    acc[1][0] = __builtin_amdgcn_mfma_f32_16x16x32_bf16(a1, bfr[0][kt], acc[1][0], 0, 0, 0);
    acc[1][1] = __builtin_amdgcn_mfma_f32_16x16x32_bf16(a1, bfr[1][kt], acc[1][1], 0, 0, 0);
  }
  #pragma unroll
  for (int nt = 0; nt < 2; ++nt){
    int colg = w * 32 + nt * 16 + lr;
    float bv = bias[colg];
    float cs = 0.f, cq = 0.f;
    #pragma unroll
    for (int mt = 0; mt < 2; ++mt){
      #pragma unroll
      for (int r = 0; r < 4; ++r){
        float y = acc[mt][nt][r] + bv;
        out[(row0 + mt * 16 + lk * 4 + r) * DD + colg] = y;
        cs += y; cq += y * y;
      }
    }
    atomicAdd(&s_sum[colg], cs);
    atomicAdd(&s_sq[colg], cq);
  }
  __syncthreads();
  if (tid < DD){
    atomicAdd(&osum[tid],      s_sum[tid]);
    atomicAdd(&osum[DD + tid], s_sq[tid]);
  }
}

// ---------------- BN2 (+ReLU except last) + residual; update fp32 h and bf16 mirror ----------------
__global__ void k_final(const float* __restrict__ zf, const float* __restrict__ stats2,
                        const float* __restrict__ gl, const float* __restrict__ bl,
                        float* __restrict__ h, u32* __restrict__ hb, int do_relu){
  int idx = blockIdx.x * 256 + threadIdx.x;   // NN*64
  int j0 = (idx & 63) * 2;
  float2 zz = ((const float2*)zf)[idx];
  float m0 = stats2[j0] * (1.0f / NN),     m1 = stats2[j0 + 1] * (1.0f / NN);
  float v0 = stats2[DD + j0] * (1.0f / NN) - m0 * m0;
  float v1 = stats2[DD + j0 + 1] * (1.0f / NN) - m1 * m1;
  float val0 = (zz.x - m0) * rsqrtf(v0 + 1e-5f) * gl[j0]     + bl[j0];
  float val1 = (zz.y - m1) * rsqrtf(v1 + 1e-5f) * gl[j0 + 1] + bl[j0 + 1];
  if (do_relu){ val0 = fmaxf(val0, 0.f); val1 = fmaxf(val1, 0.f); }
  float2 hv = ((float2*)h)[idx];
  hv.x += val0; hv.y += val1;
  ((float2*)h)[idx] = hv;
  hb[idx] = pack2(hv.x, hv.y);
}

extern "C" void kernel_launch(void* const* d_in, const int* in_sizes, int n_in,
                              void* d_out, int out_size, void* d_ws, size_t ws_size,
                              hipStream_t stream) {
  const int*   x_ids      = (const int*)d_in[0];
  const int*   edge_index = (const int*)d_in[1];
  const int*   edge_attr  = (const int*)d_in[2];
  const float* atom_emb   = (const float*)d_in[3];
  const float* bond_emb   = (const float*)d_in[4];
  const float* W1    = (const float*)d_in[5];
  const float* b1    = (const float*)d_in[6];
  const float* g1    = (const float*)d_in[7];
  const float* bt1   = (const float*)d_in[8];
  const float* W2    = (const float*)d_in[9];
  const float* b2    = (const float*)d_in[10];
  const float* eps   = (const float*)d_in[11];
  const float* g_out = (const float*)d_in[12];
  const float* b_out = (const float*)d_in[13];

  float* h  = (float*)d_out;                 // NN*DD fp32 running node state
  float* zA = (float*)d_ws;                  // NN*DD fp32 (GEMM2 out); first half doubles as bf16 z
  float* z2 = zA + NN * DD;                  // NN*DD fp32 (GEMM1 out)
  u32*   hb = (u32*)(z2 + NN * DD);          // NN*64: bf16 mirror of h
  u16*   wt = (u16*)(hb + NN * 64);          // 10*16384 bf16 transposed weights
  float* stats = (float*)(wt + 10 * 16384);  // 512: [sum1|sq1|sum2|sq2]
  int* row_start = (int*)(stats + 512);      // NN+1 (padded)
  int* cursor    = row_start + NN + 4;
  int* deg       = cursor + NN;
  int* col       = deg + NN;                 // EE
  int* bsum      = col + EE;                 // 40

  u32* zb = (u32*)zA;                        // bf16 gather output, aliases zA (disjoint lifetime)

  k_init <<<NN * 64 / 256, 256, 0, stream>>>(x_ids, atom_emb, h, hb, deg);
  k_wprep<<<10 * 16384 / 256, 256, 0, stream>>>(W1, W2, wt);
  k_count<<<EE / 256, 256, 0, stream>>>(edge_index, deg);
  k_scan1<<<40, 1024, 0, stream>>>(deg, row_start, bsum);
  k_scan2<<<40, 1024, 0, stream>>>(row_start, bsum, cursor);
  k_fill <<<EE / 256, 256, 0, stream>>>(edge_index, edge_attr, cursor, col);

  for (int l = 0; l < LL; ++l){
    k_gather<<<NN / 4, 256, 0, stream>>>(h, hb, row_start, col,
                                         bond_emb + l * 4 * DD, eps + l, zb, stats);
    k_gemm<false><<<NN / 32, 256, 0, stream>>>(zb, wt + l * 16384, b1 + l * DD,
                                               nullptr, nullptr, nullptr, z2, stats);
    k_gemm<true> <<<NN / 32, 256, 0, stream>>>(z2, wt + (LL + l) * 16384, b2 + l * DD,
                                               stats, g1 + l * DD, bt1 + l * DD, zA, stats + 2 * DD);
    k_final<<<NN * 64 / 256, 256, 0, stream>>>(zA, stats + 2 * DD,
                                               g_out + l * DD, b_out + l * DD,
                                               h, hb, (l < LL - 1) ? 1 : 0);
  }
}

// Round 5
// 750.709 us; speedup vs baseline: 1.6423x; 1.0359x over previous
//
#include <hip/hip_runtime.h>

#define NN 40000
#define EE 640000
#define DD 128
#define LL 5

typedef unsigned short u16;
typedef unsigned int   u32;
typedef __attribute__((ext_vector_type(8))) short bf8;   // 8 bf16 = 4 VGPRs
typedef __attribute__((ext_vector_type(4))) float f4;

__device__ __forceinline__ float bf2f(u32 u){ union{u32 i; float f;} x; x.i = u << 16; return x.f; }
__device__ __forceinline__ u16 f2bf(float f){
  union{float f; u32 i;} x; x.f = f;
  u32 r = x.i + 0x7FFFu + ((x.i >> 16) & 1u);
  return (u16)(r >> 16);
}
__device__ __forceinline__ u32 pack2(float a, float b){ return (u32)f2bf(a) | ((u32)f2bf(b) << 16); }

// ---------------- h0 = atom_emb[x_ids]: fp32 h (d_out) + bf16 mirror; zero deg; sentinel row ----------------
__global__ void k_init(const int* __restrict__ x_ids, const float* __restrict__ atom_emb,
                       float* __restrict__ h, u32* __restrict__ hb, int* __restrict__ deg){
  int idx = blockIdx.x * 256 + threadIdx.x;      // NN*64 (2 feats/thread)
  if (idx < NN) deg[idx] = 0;
  if (idx < 64) hb[NN * 64 + idx] = 0xFF80FF80u; // dummy node: both bf16 halves = -inf
  int n = idx >> 6, d2 = idx & 63;
  float2 v = ((const float2*)(atom_emb + x_ids[n] * DD))[d2];
  ((float2*)h)[idx] = v;
  hb[idx] = pack2(v.x, v.y);
}

// ---------------- transpose+cast weights: wt[m][n][k] = bf16(W_m[k][n]) ----------------
__global__ void k_wprep(const float* __restrict__ W1, const float* __restrict__ W2,
                        u16* __restrict__ wt){
  int idx = blockIdx.x * 256 + threadIdx.x;      // 10*16384
  int m = idx >> 14, nk = idx & 16383;
  int n = nk >> 7, k = nk & 127;
  const float* src = (m < LL) ? (W1 + m * 16384) : (W2 + (m - LL) * 16384);
  wt[idx] = f2bf(src[k * DD + n]);
}

// ---------------- CSR build over dst (segments padded to multiple of 4) ----------------
__global__ void k_count(const int* __restrict__ ei, int* __restrict__ deg){
  int e = blockIdx.x * 256 + threadIdx.x;
  atomicAdd(&deg[ei[EE + e]], 1);
}

// phase 1: per-block exclusive scan of PADDED degrees + block totals (40 blocks x 1024)
__global__ void k_scan1(const int* __restrict__ deg, int* __restrict__ rs, int* __restrict__ bsum){
  __shared__ int buf[1024];
  int tid = threadIdx.x;
  int i = blockIdx.x * 1024 + tid;
  int dv = (i < NN) ? deg[i] : 0;
  int v = (dv + 3) & ~3;                         // pad each segment to x4
  buf[tid] = v;
  __syncthreads();
  for (int off = 1; off < 1024; off <<= 1){
    int t = (tid >= off) ? buf[tid - off] : 0;
    __syncthreads();
    buf[tid] += t;
    __syncthreads();
  }
  int incl = buf[tid];
  if (i < NN) rs[i] = incl - v;
  if (tid == 1023) bsum[blockIdx.x] = incl;
}

// phase 2: add block offsets, write cursor, rs[NN]=padded total, sentinel-fill col
__global__ void k_scan2(int* __restrict__ rs, const int* __restrict__ bsum,
                        int* __restrict__ cursor, int* __restrict__ col){
  __shared__ int s_off;
  int tid = threadIdx.x;
  if (tid < 64){
    int v = (tid < 40) ? bsum[tid] : 0;
    #pragma unroll
    for (int off = 1; off < 64; off <<= 1){
      int t = __shfl_up(v, off, 64);
      if (tid >= off) v += t;
    }
    int bx = (int)blockIdx.x;
    int ex = (bx == 0) ? 0 : __shfl(v, bx - 1, 64);
    if (tid == 0) s_off = ex;
    if (bx == 0 && tid == 39) rs[NN] = v;        // total padded edge count
  }
  __syncthreads();
  int i = blockIdx.x * 1024 + tid;
  if (i < NN){
    int e = rs[i] + s_off;
    rs[i] = e;
    cursor[i] = e;
  }
  for (int t = blockIdx.x * 1024 + tid; t < EE + 3 * NN; t += 40 * 1024)
    col[t] = NN;                                 // sentinel: dummy node, attr 0
}

__global__ void k_fill(const int* __restrict__ ei, const int* __restrict__ ea,
                       int* __restrict__ cursor, int* __restrict__ col){
  int e = blockIdx.x * 256 + threadIdx.x;
  int d = ei[EE + e];
  int pos = atomicAdd(&cursor[d], 1);
  col[pos] = ei[e] | (ea[e] << 20);   // src < 2^17, attr < 4
}

// ---------------- gather: zb = bf16( (1+eps)*h + sum relu(hb[src]+bond[attr]) ); zeroes stats ----------------
__global__ void k_gather(const float* __restrict__ h, const u32* __restrict__ hb,
                         const int* __restrict__ row_start, const int* __restrict__ col,
                         const float* __restrict__ bond_l, const float* __restrict__ eps_l,
                         u32* __restrict__ zb, float* __restrict__ stats){
  __shared__ float2 s_bond[4 * 64];
  __shared__ float s_eps;
  int tid = threadIdx.x;
  if (blockIdx.x == 0){                           // stats zeroed before gemm1 launches (stream order)
    stats[tid] = 0.f; stats[256 + tid] = 0.f;
  }
  if (tid < 256) s_bond[tid] = ((const float2*)bond_l)[tid];
  if (tid == 0) s_eps = 1.0f + eps_l[0];
  __syncthreads();
  int wid = tid >> 6, lane = tid & 63;
  int v = blockIdx.x * 4 + wid;                   // NN divisible by 4
  int sbeg = __builtin_amdgcn_readfirstlane(row_start[v]);      // multiple of 4
  int send = __builtin_amdgcn_readfirstlane(row_start[v + 1]);  // multiple of 4
  float a0 = 0.f, a1 = 0.f, b0 = 0.f, b1 = 0.f, c0 = 0.f, c1 = 0.f, d0 = 0.f, d1 = 0.f;
  int i = sbeg;
  for (; i + 8 <= send; i += 8){
    int4 ca = *(const int4*)(col + i);
    int4 cb = *(const int4*)(col + i + 4);
    u32 h0 = hb[(ca.x & 0xFFFFF) * 64 + lane];
    u32 h1 = hb[(ca.y & 0xFFFFF) * 64 + lane];
    u32 h2 = hb[(ca.z & 0xFFFFF) * 64 + lane];
    u32 h3 = hb[(ca.w & 0xFFFFF) * 64 + lane];
    u32 h4 = hb[(cb.x & 0xFFFFF) * 64 + lane];
    u32 h5 = hb[(cb.y & 0xFFFFF) * 64 + lane];
    u32 h6 = hb[(cb.z & 0xFFFFF) * 64 + lane];
    u32 h7 = hb[(cb.w & 0xFFFFF) * 64 + lane];
    float2 bb0 = s_bond[(ca.x >> 20) * 64 + lane];
    float2 bb1 = s_bond[(ca.y >> 20) * 64 + lane];
    float2 bb2 = s_bond[(ca.z >> 20) * 64 + lane];
    float2 bb3 = s_bond[(ca.w >> 20) * 64 + lane];
    float2 bb4 = s_bond[(cb.x >> 20) * 64 + lane];
    float2 bb5 = s_bond[(cb.y >> 20) * 64 + lane];
    float2 bb6 = s_bond[(cb.z >> 20) * 64 + lane];
    float2 bb7 = s_bond[(cb.w >> 20) * 64 + lane];
    a0 += fmaxf(bf2f(h0 & 0xFFFFu) + bb0.x, 0.f);
    a1 += fmaxf(bf2f(h0 >> 16)     + bb0.y, 0.f);
    b0 += fmaxf(bf2f(h1 & 0xFFFFu) + bb1.x, 0.f);
    b1 += fmaxf(bf2f(h1 >> 16)     + bb1.y, 0.f);
    c0 += fmaxf(bf2f(h2 & 0xFFFFu) + bb2.x, 0.f);
    c1 += fmaxf(bf2f(h2 >> 16)     + bb2.y, 0.f);
    d0 += fmaxf(bf2f(h3 & 0xFFFFu) + bb3.x, 0.f);
    d1 += fmaxf(bf2f(h3 >> 16)     + bb3.y, 0.f);
    a0 += fmaxf(bf2f(h4 & 0xFFFFu) + bb4.x, 0.f);
    a1 += fmaxf(bf2f(h4 >> 16)     + bb4.y, 0.f);
    b0 += fmaxf(bf2f(h5 & 0xFFFFu) + bb5.x, 0.f);
    b1 += fmaxf(bf2f(h5 >> 16)     + bb5.y, 0.f);
    c0 += fmaxf(bf2f(h6 & 0xFFFFu) + bb6.x, 0.f);
    c1 += fmaxf(bf2f(h6 >> 16)     + bb6.y, 0.f);
    d0 += fmaxf(bf2f(h7 & 0xFFFFu) + bb7.x, 0.f);
    d1 += fmaxf(bf2f(h7 >> 16)     + bb7.y, 0.f);
  }
  if (i < send){                                  // exactly 4 remain (padded)
    int4 ca = *(const int4*)(col + i);
    u32 h0 = hb[(ca.x & 0xFFFFF) * 64 + lane];
    u32 h1 = hb[(ca.y & 0xFFFFF) * 64 + lane];
    u32 h2 = hb[(ca.z & 0xFFFFF) * 64 + lane];
    u32 h3 = hb[(ca.w & 0xFFFFF) * 64 + lane];
    float2 bb0 = s_bond[(ca.x >> 20) * 64 + lane];
    float2 bb1 = s_bond[(ca.y >> 20) * 64 + lane];
    float2 bb2 = s_bond[(ca.z >> 20) * 64 + lane];
    float2 bb3 = s_bond[(ca.w >> 20) * 64 + lane];
    a0 += fmaxf(bf2f(h0 & 0xFFFFu) + bb0.x, 0.f);
    a1 += fmaxf(bf2f(h0 >> 16)     + bb0.y, 0.f);
    b0 += fmaxf(bf2f(h1 & 0xFFFFu) + bb1.x, 0.f);
    b1 += fmaxf(bf2f(h1 >> 16)     + bb1.y, 0.f);
    c0 += fmaxf(bf2f(h2 & 0xFFFFu) + bb2.x, 0.f);
    c1 += fmaxf(bf2f(h2 >> 16)     + bb2.y, 0.f);
    d0 += fmaxf(bf2f(h3 & 0xFFFFu) + bb3.x, 0.f);
    d1 += fmaxf(bf2f(h3 >> 16)     + bb3.y, 0.f);
  }
  float2 hv = ((const float2*)h)[v * 64 + lane];
  zb[v * 64 + lane] = pack2(s_eps * hv.x + a0 + b0 + c0 + d0,
                            s_eps * hv.y + a1 + b1 + c1 + d1);
}

// ---------------- MFMA GEMM: out(bf16) = A(bf16) @ W + b, fused col stats; BN+ReLU on input if BN ----------------
template<bool BN>
__global__ __launch_bounds__(256) void k_gemm(const u16* __restrict__ Asrc,
    const u16* __restrict__ Wt,               // bf16 Wt[n][k]
    const float* __restrict__ bias,
    const float* __restrict__ stats_in, const float* __restrict__ g, const float* __restrict__ bt,
    u16* __restrict__ out, float* __restrict__ osum){
  __shared__ u16 sA[32 * 136];                // padded rows: 2-way bank aliasing (free)
  __shared__ float s_scale[DD], s_shift[DD];
  __shared__ float s_sum[DD], s_sq[DD];
  int tid = threadIdx.x;
  int row0 = blockIdx.x * 32;                 // 1250 blocks exact
  if (tid < DD){
    s_sum[tid] = 0.f; s_sq[tid] = 0.f;
    if (BN){
      float m   = stats_in[tid] * (1.0f / NN);
      float var = stats_in[DD + tid] * (1.0f / NN) - m * m;
      float inv = rsqrtf(var + 1e-5f);
      float sc  = inv * g[tid];
      s_scale[tid] = sc;
      s_shift[tid] = bt[tid] - m * sc;
    }
  }
  __syncthreads();
  #pragma unroll
  for (int c0 = 0; c0 < 2; ++c0){
    int c = tid + c0 * 256;
    int row = c >> 4, off = (c & 15) * 8;
    uint4 v = *(const uint4*)(Asrc + (row0 + row) * DD + off);
    if (BN){
      u32 wv[4] = {v.x, v.y, v.z, v.w};
      union { u16 o[8]; uint4 v; } u;
      #pragma unroll
      for (int j = 0; j < 4; ++j){
        float y0 = bf2f(wv[j] & 0xFFFFu) * s_scale[off + 2*j]     + s_shift[off + 2*j];
        float y1 = bf2f(wv[j] >> 16)     * s_scale[off + 2*j + 1] + s_shift[off + 2*j + 1];
        u.o[2*j]     = f2bf(fmaxf(y0, 0.f));
        u.o[2*j + 1] = f2bf(fmaxf(y1, 0.f));
      }
      v = u.v;
    }
    *(uint4*)(sA + row * 136 + off) = v;
  }
  int w = tid >> 6, lane = tid & 63, lr = lane & 15, lk = lane >> 4;
  bf8 bfr[2][4];
  #pragma unroll
  for (int nt = 0; nt < 2; ++nt){
    int n = w * 32 + nt * 16 + lr;
    #pragma unroll
    for (int kt = 0; kt < 4; ++kt)
      bfr[nt][kt] = *(const bf8*)(Wt + n * DD + kt * 32 + lk * 8);
  }
  __syncthreads();
  f4 acc[2][2];
  #pragma unroll
  for (int mt = 0; mt < 2; ++mt)
    #pragma unroll
    for (int nt = 0; nt < 2; ++nt) acc[mt][nt] = (f4){0.f, 0.f, 0.f, 0.f};
  #pragma unroll
  for (int kt = 0; kt < 4; ++kt){
    bf8 a0 = *(const bf8*)(sA + lr * 136        + kt * 32 + lk * 8);
    bf8 a1 = *(const bf8*)(sA + (16 + lr) * 136 + kt * 32 + lk * 8);
    acc[0][0] = __builtin_amdgcn_mfma_f32_16x16x32_bf16(a0, bfr[0][kt], acc[0][0], 0, 0, 0);
    acc[0][1] = __builtin_amdgcn_mfma_f32_16x16x32_bf16(a0, bfr[1][kt], acc[0][1], 0, 0, 0);
    acc[1][0] = __builtin_amdgcn_mfma_f32_16x16x32_bf16(a1, bfr[0][kt], acc[1][0], 0, 0, 0);
    acc[1][1] = __builtin_amdgcn_mfma_f32_16x16x32_bf16(a1, bfr[1][kt], acc[1][1], 0, 0, 0);
  }
  // epilogue: C/D layout col=lane&15, row=(lane>>4)*4+reg; stats from bf16-rounded values
  #pragma unroll
  for (int nt = 0; nt < 2; ++nt){
    int colg = w * 32 + nt * 16 + lr;
    float bv = bias[colg];
    float cs = 0.f, cq = 0.f;
    #pragma unroll
    for (int mt = 0; mt < 2; ++mt){
      #pragma unroll
      for (int r = 0; r < 4; ++r){
        u16 yb = f2bf(acc[mt][nt][r] + bv);
        float yr = bf2f(yb);
        out[(row0 + mt * 16 + lk * 4 + r) * DD + colg] = yb;
        cs += yr; cq += yr * yr;
      }
    }
    atomicAdd(&s_sum[colg], cs);
    atomicAdd(&s_sq[colg], cq);
  }
  __syncthreads();
  if (tid < DD){
    atomicAdd(&osum[tid],      s_sum[tid]);
    atomicAdd(&osum[DD + tid], s_sq[tid]);
  }
}

// ---------------- BN2 (+ReLU except last) + residual; update fp32 h and bf16 mirror ----------------
__global__ void k_final(const u32* __restrict__ zf, const float* __restrict__ stats2,
                        const float* __restrict__ gl, const float* __restrict__ bl,
                        float* __restrict__ h, u32* __restrict__ hb, int do_relu){
  int idx = blockIdx.x * 256 + threadIdx.x;   // NN*64
  int j0 = (idx & 63) * 2;
  u32 zz = zf[idx];
  float z0 = bf2f(zz & 0xFFFFu), z1 = bf2f(zz >> 16);
  float m0 = stats2[j0] * (1.0f / NN),     m1 = stats2[j0 + 1] * (1.0f / NN);
  float v0 = stats2[DD + j0] * (1.0f / NN) - m0 * m0;
  float v1 = stats2[DD + j0 + 1] * (1.0f / NN) - m1 * m1;
  float val0 = (z0 - m0) * rsqrtf(v0 + 1e-5f) * gl[j0]     + bl[j0];
  float val1 = (z1 - m1) * rsqrtf(v1 + 1e-5f) * gl[j0 + 1] + bl[j0 + 1];
  if (do_relu){ val0 = fmaxf(val0, 0.f); val1 = fmaxf(val1, 0.f); }
  float2 hv = ((float2*)h)[idx];
  hv.x += val0; hv.y += val1;
  ((float2*)h)[idx] = hv;
  hb[idx] = pack2(hv.x, hv.y);
}

extern "C" void kernel_launch(void* const* d_in, const int* in_sizes, int n_in,
                              void* d_out, int out_size, void* d_ws, size_t ws_size,
                              hipStream_t stream) {
  const int*   x_ids      = (const int*)d_in[0];
  const int*   edge_index = (const int*)d_in[1];
  const int*   edge_attr  = (const int*)d_in[2];
  const float* atom_emb   = (const float*)d_in[3];
  const float* bond_emb   = (const float*)d_in[4];
  const float* W1    = (const float*)d_in[5];
  const float* b1    = (const float*)d_in[6];
  const float* g1    = (const float*)d_in[7];
  const float* bt1   = (const float*)d_in[8];
  const float* W2    = (const float*)d_in[9];
  const float* b2    = (const float*)d_in[10];
  const float* eps   = (const float*)d_in[11];
  const float* g_out = (const float*)d_in[12];
  const float* b_out = (const float*)d_in[13];

  float* h   = (float*)d_out;                 // NN*DD fp32 running node state
  u32*   zb  = (u32*)d_ws;                    // NN*64: bf16 gather out
  u32*   z2b = zb  + NN * 64;                 // NN*64: bf16 gemm1 out
  u32*   zAb = z2b + NN * 64;                 // NN*64: bf16 gemm2 out
  u32*   hb  = zAb + NN * 64;                 // (NN+1)*64: bf16 mirror of h + sentinel row
  u16*   wt  = (u16*)(hb + (NN + 1) * 64);    // 10*16384 bf16 transposed weights
  float* stats = (float*)(wt + 10 * 16384);   // 512: [sum1|sq1|sum2|sq2]
  int* row_start = (int*)(stats + 512);       // NN+4
  int* cursor    = row_start + NN + 4;
  int* deg       = cursor + NN;
  int* col       = deg + NN;                  // EE + 3*NN (padded)
  int* bsum      = col + EE + 3 * NN;         // 40

  k_init <<<NN * 64 / 256, 256, 0, stream>>>(x_ids, atom_emb, h, hb, deg);
  k_wprep<<<10 * 16384 / 256, 256, 0, stream>>>(W1, W2, wt);
  k_count<<<EE / 256, 256, 0, stream>>>(edge_index, deg);
  k_scan1<<<40, 1024, 0, stream>>>(deg, row_start, bsum);
  k_scan2<<<40, 1024, 0, stream>>>(row_start, bsum, cursor, col);
  k_fill <<<EE / 256, 256, 0, stream>>>(edge_index, edge_attr, cursor, col);

  for (int l = 0; l < LL; ++l){
    k_gather<<<NN / 4, 256, 0, stream>>>(h, hb, row_start, col,
                                         bond_emb + l * 4 * DD, eps + l, zb, stats);
    k_gemm<false><<<NN / 32, 256, 0, stream>>>((const u16*)zb, wt + l * 16384, b1 + l * DD,
                                               nullptr, nullptr, nullptr, (u16*)z2b, stats);
    k_gemm<true> <<<NN / 32, 256, 0, stream>>>((const u16*)z2b, wt + (LL + l) * 16384, b2 + l * DD,
                                               stats, g1 + l * DD, bt1 + l * DD, (u16*)zAb, stats + 2 * DD);
    k_final<<<NN * 64 / 256, 256, 0, stream>>>(zAb, stats + 2 * DD,
                                               g_out + l * DD, b_out + l * DD,
                                               h, hb, (l < LL - 1) ? 1 : 0);
  }
}

// Round 6
// 512.177 us; speedup vs baseline: 2.4071x; 1.4657x over previous
//
#include <hip/hip_runtime.h>

#define NN 40000
#define EE 640000
#define DD 128
#define LL 5

typedef unsigned short u16;
typedef unsigned int   u32;
typedef __attribute__((ext_vector_type(8))) short bf8;   // 8 bf16 = 4 VGPRs
typedef __attribute__((ext_vector_type(4))) float f4;

__device__ __forceinline__ float bf2f(u32 u){ union{u32 i; float f;} x; x.i = u << 16; return x.f; }
__device__ __forceinline__ u16 f2bf(float f){
  union{float f; u32 i;} x; x.f = f;
  u32 r = x.i + 0x7FFFu + ((x.i >> 16) & 1u);
  return (u16)(r >> 16);
}
__device__ __forceinline__ u32 pack2(float a, float b){ return (u32)f2bf(a) | ((u32)f2bf(b) << 16); }

// ---------------- merged prologue: init h/hb/deg/sentinel | wprep | count ----------------
__global__ void k_pre(const int* __restrict__ x_ids, const float* __restrict__ atom_emb,
                      float* __restrict__ h, u32* __restrict__ hb, int* __restrict__ deg,
                      const float* __restrict__ W1, const float* __restrict__ W2,
                      u16* __restrict__ wt, const int* __restrict__ ei){
  int bid = blockIdx.x, tid = threadIdx.x;
  if (bid < 10000){                               // init: NN*64 items
    int idx = bid * 256 + tid;
    if (idx < NN) deg[idx] = 0;
    if (idx < 64) hb[NN * 64 + idx] = 0xFF80FF80u;  // dummy node: both halves -inf
    int n = idx >> 6, d2 = idx & 63;
    float2 v = ((const float2*)(atom_emb + x_ids[n] * DD))[d2];
    ((float2*)h)[idx] = v;
    hb[idx] = pack2(v.x, v.y);
  } else if (bid < 10640){                        // wprep: 10*16384 items
    int idx = (bid - 10000) * 256 + tid;
    int m = idx >> 14, nk = idx & 16383;
    int n = nk >> 7, k = nk & 127;
    const float* src = (m < LL) ? (W1 + m * 16384) : (W2 + (m - LL) * 16384);
    wt[idx] = f2bf(src[k * DD + n]);
  } else {                                        // count: EE items
    int e = (bid - 10640) * 256 + tid;
    atomicAdd(&deg[ei[EE + e]], 1);
  }
}

// phase 1: per-block exclusive scan of PADDED degrees + block totals (40 blocks x 1024)
__global__ void k_scan1(const int* __restrict__ deg, int* __restrict__ rs, int* __restrict__ bsum){
  __shared__ int buf[1024];
  int tid = threadIdx.x;
  int i = blockIdx.x * 1024 + tid;
  int dv = (i < NN) ? deg[i] : 0;
  int v = (dv + 3) & ~3;                         // pad each segment to x4
  buf[tid] = v;
  __syncthreads();
  for (int off = 1; off < 1024; off <<= 1){
    int t = (tid >= off) ? buf[tid - off] : 0;
    __syncthreads();
    buf[tid] += t;
    __syncthreads();
  }
  int incl = buf[tid];
  if (i < NN) rs[i] = incl - v;
  if (tid == 1023) bsum[blockIdx.x] = incl;
}

// phase 2: add block offsets, write cursor, rs[NN]=padded total, sentinel-fill col
__global__ void k_scan2(int* __restrict__ rs, const int* __restrict__ bsum,
                        int* __restrict__ cursor, int* __restrict__ col){
  __shared__ int s_off;
  int tid = threadIdx.x;
  if (tid < 64){
    int v = (tid < 40) ? bsum[tid] : 0;
    #pragma unroll
    for (int off = 1; off < 64; off <<= 1){
      int t = __shfl_up(v, off, 64);
      if (tid >= off) v += t;
    }
    int bx = (int)blockIdx.x;
    int ex = (bx == 0) ? 0 : __shfl(v, bx - 1, 64);
    if (tid == 0) s_off = ex;
    if (bx == 0 && tid == 39) rs[NN] = v;        // total padded edge count
  }
  __syncthreads();
  int i = blockIdx.x * 1024 + tid;
  if (i < NN){
    int e = rs[i] + s_off;
    rs[i] = e;
    cursor[i] = e;
  }
  for (int t = blockIdx.x * 1024 + tid; t < EE + 3 * NN; t += 40 * 1024)
    col[t] = NN;                                 // sentinel: dummy node, attr 0
}

__global__ void k_fill(const int* __restrict__ ei, const int* __restrict__ ea,
                       int* __restrict__ cursor, int* __restrict__ col){
  int e = blockIdx.x * 256 + threadIdx.x;
  int d = ei[EE + e];
  int pos = atomicAdd(&cursor[d], 1);
  col[pos] = ei[e] | (ea[e] << 20);   // src < 2^16, attr < 4
}

// ---------------- gather: zb = bf16( (1+eps)*h + sum relu(hb[src]+bond[attr]) ); zeroes stats ----------------
// 1024-thread blocks: 16 waves, 1 node/wave, 2 blocks/CU -> 32 waves/CU
__global__ __launch_bounds__(1024) void k_gather(
                         const float* __restrict__ h, const u32* __restrict__ hb,
                         const int* __restrict__ row_start, const int* __restrict__ col,
                         const float* __restrict__ bond_l, const float* __restrict__ eps_l,
                         u32* __restrict__ zb, float* __restrict__ stats_all){
  __shared__ float2 s_bond[4 * 64];
  __shared__ float s_eps;
  int tid = threadIdx.x;
  if (blockIdx.x < 2){                            // zero 4096 stat floats (2 sets x 8 slices x 256)
    stats_all[blockIdx.x * 2048 + tid] = 0.f;
    stats_all[blockIdx.x * 2048 + 1024 + tid] = 0.f;
  }
  if (tid < 256) s_bond[tid] = ((const float2*)bond_l)[tid];
  if (tid == 0) s_eps = 1.0f + eps_l[0];
  __syncthreads();
  int wid = tid >> 6, lane = tid & 63;
  int v = blockIdx.x * 16 + wid;                  // NN divisible by 16
  int sbeg = __builtin_amdgcn_readfirstlane(row_start[v]);      // multiple of 4
  int send = __builtin_amdgcn_readfirstlane(row_start[v + 1]);  // multiple of 4
  float a0 = 0.f, a1 = 0.f, b0 = 0.f, b1 = 0.f, c0 = 0.f, c1 = 0.f, d0 = 0.f, d1 = 0.f;
  int i = sbeg;
  for (; i + 8 <= send; i += 8){
    int4 ca = *(const int4*)(col + i);
    int4 cb = *(const int4*)(col + i + 4);
    u32 h0 = hb[(ca.x & 0xFFFFF) * 64 + lane];
    u32 h1 = hb[(ca.y & 0xFFFFF) * 64 + lane];
    u32 h2 = hb[(ca.z & 0xFFFFF) * 64 + lane];
    u32 h3 = hb[(ca.w & 0xFFFFF) * 64 + lane];
    u32 h4 = hb[(cb.x & 0xFFFFF) * 64 + lane];
    u32 h5 = hb[(cb.y & 0xFFFFF) * 64 + lane];
    u32 h6 = hb[(cb.z & 0xFFFFF) * 64 + lane];
    u32 h7 = hb[(cb.w & 0xFFFFF) * 64 + lane];
    float2 bb0 = s_bond[(ca.x >> 20) * 64 + lane];
    float2 bb1 = s_bond[(ca.y >> 20) * 64 + lane];
    float2 bb2 = s_bond[(ca.z >> 20) * 64 + lane];
    float2 bb3 = s_bond[(ca.w >> 20) * 64 + lane];
    float2 bb4 = s_bond[(cb.x >> 20) * 64 + lane];
    float2 bb5 = s_bond[(cb.y >> 20) * 64 + lane];
    float2 bb6 = s_bond[(cb.z >> 20) * 64 + lane];
    float2 bb7 = s_bond[(cb.w >> 20) * 64 + lane];
    a0 += fmaxf(bf2f(h0 & 0xFFFFu) + bb0.x, 0.f);
    a1 += fmaxf(bf2f(h0 >> 16)     + bb0.y, 0.f);
    b0 += fmaxf(bf2f(h1 & 0xFFFFu) + bb1.x, 0.f);
    b1 += fmaxf(bf2f(h1 >> 16)     + bb1.y, 0.f);
    c0 += fmaxf(bf2f(h2 & 0xFFFFu) + bb2.x, 0.f);
    c1 += fmaxf(bf2f(h2 >> 16)     + bb2.y, 0.f);
    d0 += fmaxf(bf2f(h3 & 0xFFFFu) + bb3.x, 0.f);
    d1 += fmaxf(bf2f(h3 >> 16)     + bb3.y, 0.f);
    a0 += fmaxf(bf2f(h4 & 0xFFFFu) + bb4.x, 0.f);
    a1 += fmaxf(bf2f(h4 >> 16)     + bb4.y, 0.f);
    b0 += fmaxf(bf2f(h5 & 0xFFFFu) + bb5.x, 0.f);
    b1 += fmaxf(bf2f(h5 >> 16)     + bb5.y, 0.f);
    c0 += fmaxf(bf2f(h6 & 0xFFFFu) + bb6.x, 0.f);
    c1 += fmaxf(bf2f(h6 >> 16)     + bb6.y, 0.f);
    d0 += fmaxf(bf2f(h7 & 0xFFFFu) + bb7.x, 0.f);
    d1 += fmaxf(bf2f(h7 >> 16)     + bb7.y, 0.f);
  }
  if (i < send){                                  // exactly 4 remain (padded)
    int4 ca = *(const int4*)(col + i);
    u32 h0 = hb[(ca.x & 0xFFFFF) * 64 + lane];
    u32 h1 = hb[(ca.y & 0xFFFFF) * 64 + lane];
    u32 h2 = hb[(ca.z & 0xFFFFF) * 64 + lane];
    u32 h3 = hb[(ca.w & 0xFFFFF) * 64 + lane];
    float2 bb0 = s_bond[(ca.x >> 20) * 64 + lane];
    float2 bb1 = s_bond[(ca.y >> 20) * 64 + lane];
    float2 bb2 = s_bond[(ca.z >> 20) * 64 + lane];
    float2 bb3 = s_bond[(ca.w >> 20) * 64 + lane];
    a0 += fmaxf(bf2f(h0 & 0xFFFFu) + bb0.x, 0.f);
    a1 += fmaxf(bf2f(h0 >> 16)     + bb0.y, 0.f);
    b0 += fmaxf(bf2f(h1 & 0xFFFFu) + bb1.x, 0.f);
    b1 += fmaxf(bf2f(h1 >> 16)     + bb1.y, 0.f);
    c0 += fmaxf(bf2f(h2 & 0xFFFFu) + bb2.x, 0.f);
    c1 += fmaxf(bf2f(h2 >> 16)     + bb2.y, 0.f);
    d0 += fmaxf(bf2f(h3 & 0xFFFFu) + bb3.x, 0.f);
    d1 += fmaxf(bf2f(h3 >> 16)     + bb3.y, 0.f);
  }
  float2 hv = ((const float2*)h)[v * 64 + lane];
  zb[v * 64 + lane] = pack2(s_eps * hv.x + a0 + b0 + c0 + d0,
                            s_eps * hv.y + a1 + b1 + c1 + d1);
}

// ---------------- MFMA GEMM: out(bf16) = A(bf16) @ W + b; 8-way sliced col stats; BN+ReLU in if BN ----------------
template<bool BN>
__global__ __launch_bounds__(256) void k_gemm(const u16* __restrict__ Asrc,
    const u16* __restrict__ Wt,               // bf16 Wt[n][k]
    const float* __restrict__ bias,
    const float* __restrict__ stats_in,       // 8 slices x [sum128|sq128]
    const float* __restrict__ g, const float* __restrict__ bt,
    u16* __restrict__ out, float* __restrict__ osum){
  __shared__ u16 sA[32 * 136];                // padded rows: 2-way bank aliasing (free)
  __shared__ float s_scale[DD], s_shift[DD];
  __shared__ float s_sum[DD], s_sq[DD];
  int tid = threadIdx.x;
  int row0 = blockIdx.x * 32;                 // 1250 blocks exact
  if (tid < DD){
    s_sum[tid] = 0.f; s_sq[tid] = 0.f;
    if (BN){
      float s = 0.f, q = 0.f;
      #pragma unroll
      for (int s8 = 0; s8 < 8; ++s8){
        s += stats_in[s8 * 256 + tid];
        q += stats_in[s8 * 256 + DD + tid];
      }
      float m   = s * (1.0f / NN);
      float var = q * (1.0f / NN) - m * m;
      float inv = rsqrtf(var + 1e-5f);
      float sc  = inv * g[tid];
      s_scale[tid] = sc;
      s_shift[tid] = bt[tid] - m * sc;
    }
  }
  __syncthreads();
  #pragma unroll
  for (int c0 = 0; c0 < 2; ++c0){
    int c = tid + c0 * 256;
    int row = c >> 4, off = (c & 15) * 8;
    uint4 v = *(const uint4*)(Asrc + (row0 + row) * DD + off);
    if (BN){
      u32 wv[4] = {v.x, v.y, v.z, v.w};
      union { u16 o[8]; uint4 v; } u;
      #pragma unroll
      for (int j = 0; j < 4; ++j){
        float y0 = bf2f(wv[j] & 0xFFFFu) * s_scale[off + 2*j]     + s_shift[off + 2*j];
        float y1 = bf2f(wv[j] >> 16)     * s_scale[off + 2*j + 1] + s_shift[off + 2*j + 1];
        u.o[2*j]     = f2bf(fmaxf(y0, 0.f));
        u.o[2*j + 1] = f2bf(fmaxf(y1, 0.f));
      }
      v = u.v;
    }
    *(uint4*)(sA + row * 136 + off) = v;
  }
  int w = tid >> 6, lane = tid & 63, lr = lane & 15, lk = lane >> 4;
  bf8 bfr[2][4];
  #pragma unroll
  for (int nt = 0; nt < 2; ++nt){
    int n = w * 32 + nt * 16 + lr;
    #pragma unroll
    for (int kt = 0; kt < 4; ++kt)
      bfr[nt][kt] = *(const bf8*)(Wt + n * DD + kt * 32 + lk * 8);
  }
  __syncthreads();
  f4 acc[2][2];
  #pragma unroll
  for (int mt = 0; mt < 2; ++mt)
    #pragma unroll
    for (int nt = 0; nt < 2; ++nt) acc[mt][nt] = (f4){0.f, 0.f, 0.f, 0.f};
  #pragma unroll
  for (int kt = 0; kt < 4; ++kt){
    bf8 a0 = *(const bf8*)(sA + lr * 136        + kt * 32 + lk * 8);
    bf8 a1 = *(const bf8*)(sA + (16 + lr) * 136 + kt * 32 + lk * 8);
    acc[0][0] = __builtin_amdgcn_mfma_f32_16x16x32_bf16(a0, bfr[0][kt], acc[0][0], 0, 0, 0);
    acc[0][1] = __builtin_amdgcn_mfma_f32_16x16x32_bf16(a0, bfr[1][kt], acc[0][1], 0, 0, 0);
    acc[1][0] = __builtin_amdgcn_mfma_f32_16x16x32_bf16(a1, bfr[0][kt], acc[1][0], 0, 0, 0);
    acc[1][1] = __builtin_amdgcn_mfma_f32_16x16x32_bf16(a1, bfr[1][kt], acc[1][1], 0, 0, 0);
  }
  // epilogue: C/D layout col=lane&15, row=(lane>>4)*4+reg; stats from bf16-rounded values
  #pragma unroll
  for (int nt = 0; nt < 2; ++nt){
    int colg = w * 32 + nt * 16 + lr;
    float bv = bias[colg];
    float cs = 0.f, cq = 0.f;
    #pragma unroll
    for (int mt = 0; mt < 2; ++mt){
      #pragma unroll
      for (int r = 0; r < 4; ++r){
        u16 yb = f2bf(acc[mt][nt][r] + bv);
        float yr = bf2f(yb);
        out[(row0 + mt * 16 + lk * 4 + r) * DD + colg] = yb;
        cs += yr; cq += yr * yr;
      }
    }
    atomicAdd(&s_sum[colg], cs);
    atomicAdd(&s_sq[colg], cq);
  }
  __syncthreads();
  float* slice = osum + (blockIdx.x & 7) * 256;   // 8-way contention split
  if (tid < DD){
    atomicAdd(&slice[tid],      s_sum[tid]);
    atomicAdd(&slice[DD + tid], s_sq[tid]);
  }
}

// ---------------- BN2 (+ReLU except last) + residual; update fp32 h and bf16 mirror ----------------
__global__ void k_final(const u32* __restrict__ zf, const float* __restrict__ stats2,
                        const float* __restrict__ gl, const float* __restrict__ bl,
                        float* __restrict__ h, u32* __restrict__ hb, int do_relu){
  __shared__ float s_scale[DD], s_shift[DD];
  int tid = threadIdx.x;
  if (tid < DD){
    float s = 0.f, q = 0.f;
    #pragma unroll
    for (int s8 = 0; s8 < 8; ++s8){
      s += stats2[s8 * 256 + tid];
      q += stats2[s8 * 256 + DD + tid];
    }
    float m   = s * (1.0f / NN);
    float var = q * (1.0f / NN) - m * m;
    float inv = rsqrtf(var + 1e-5f);
    float sc  = inv * gl[tid];
    s_scale[tid] = sc;
    s_shift[tid] = bl[tid] - m * sc;
  }
  __syncthreads();
  int idx = blockIdx.x * 256 + tid;           // NN*64
  int j0 = (idx & 63) * 2;
  u32 zz = zf[idx];
  float val0 = bf2f(zz & 0xFFFFu) * s_scale[j0]     + s_shift[j0];
  float val1 = bf2f(zz >> 16)     * s_scale[j0 + 1] + s_shift[j0 + 1];
  if (do_relu){ val0 = fmaxf(val0, 0.f); val1 = fmaxf(val1, 0.f); }
  float2 hv = ((float2*)h)[idx];
  hv.x += val0; hv.y += val1;
  ((float2*)h)[idx] = hv;
  hb[idx] = pack2(hv.x, hv.y);
}

extern "C" void kernel_launch(void* const* d_in, const int* in_sizes, int n_in,
                              void* d_out, int out_size, void* d_ws, size_t ws_size,
                              hipStream_t stream) {
  const int*   x_ids      = (const int*)d_in[0];
  const int*   edge_index = (const int*)d_in[1];
  const int*   edge_attr  = (const int*)d_in[2];
  const float* atom_emb   = (const float*)d_in[3];
  const float* bond_emb   = (const float*)d_in[4];
  const float* W1    = (const float*)d_in[5];
  const float* b1    = (const float*)d_in[6];
  const float* g1    = (const float*)d_in[7];
  const float* bt1   = (const float*)d_in[8];
  const float* W2    = (const float*)d_in[9];
  const float* b2    = (const float*)d_in[10];
  const float* eps   = (const float*)d_in[11];
  const float* g_out = (const float*)d_in[12];
  const float* b_out = (const float*)d_in[13];

  float* h   = (float*)d_out;                 // NN*DD fp32 running node state
  u32*   zb  = (u32*)d_ws;                    // NN*64: bf16 gather out
  u32*   z2b = zb  + NN * 64;                 // NN*64: bf16 gemm1 out
  u32*   zAb = z2b + NN * 64;                 // NN*64: bf16 gemm2 out
  u32*   hb  = zAb + NN * 64;                 // (NN+1)*64: bf16 mirror of h + sentinel row
  u16*   wt  = (u16*)(hb + (NN + 1) * 64);    // 10*16384 bf16 transposed weights
  float* stats = (float*)(wt + 10 * 16384);   // 4096: 2 sets x 8 slices x [sum128|sq128]
  int* row_start = (int*)(stats + 4096);      // NN+4
  int* cursor    = row_start + NN + 4;
  int* deg       = cursor + NN;
  int* col       = deg + NN;                  // EE + 3*NN (padded)
  int* bsum      = col + EE + 3 * NN;         // 40

  k_pre  <<<13140, 256, 0, stream>>>(x_ids, atom_emb, h, hb, deg, W1, W2, wt, edge_index);
  k_scan1<<<40, 1024, 0, stream>>>(deg, row_start, bsum);
  k_scan2<<<40, 1024, 0, stream>>>(row_start, bsum, cursor, col);
  k_fill <<<EE / 256, 256, 0, stream>>>(edge_index, edge_attr, cursor, col);

  for (int l = 0; l < LL; ++l){
    k_gather<<<NN / 16, 1024, 0, stream>>>(h, hb, row_start, col,
                                           bond_emb + l * 4 * DD, eps + l, zb, stats);
    k_gemm<false><<<NN / 32, 256, 0, stream>>>((const u16*)zb, wt + l * 16384, b1 + l * DD,
                                               nullptr, nullptr, nullptr, (u16*)z2b, stats);
    k_gemm<true> <<<NN / 32, 256, 0, stream>>>((const u16*)z2b, wt + (LL + l) * 16384, b2 + l * DD,
                                               stats, g1 + l * DD, bt1 + l * DD, (u16*)zAb, stats + 2048);
    k_final<<<NN * 64 / 256, 256, 0, stream>>>(zAb, stats + 2048,
                                               g_out + l * DD, b_out + l * DD,
                                               h, hb, (l < LL - 1) ? 1 : 0);
  }
}

// Round 7
// 486.187 us; speedup vs baseline: 2.5358x; 1.0535x over previous
//
#include <hip/hip_runtime.h>

#define NN 40000
#define EE 640000
#define DD 128
#define LL 5
#define NB 157          // buckets of 256 dst nodes
#define CAP 8192        // slots per bucket (mean 4096, sigma ~64)

typedef unsigned short u16;
typedef unsigned int   u32;
typedef __attribute__((ext_vector_type(8))) short bf8;   // 8 bf16 = 4 VGPRs
typedef __attribute__((ext_vector_type(4))) float f4;

__device__ __forceinline__ float bf2f(u32 u){ union{u32 i; float f;} x; x.i = u << 16; return x.f; }
__device__ __forceinline__ u16 f2bf(float f){
  union{float f; u32 i;} x; x.f = f;
  u32 r = x.i + 0x7FFFu + ((x.i >> 16) & 1u);
  return (u16)(r >> 16);
}
__device__ __forceinline__ u32 pack2(float a, float b){ return (u32)f2bf(a) | ((u32)f2bf(b) << 16); }

// ---------------- merged prologue: init h/hb/deg/gcur/sentinel | wprep | count ----------------
__global__ void k_pre(const int* __restrict__ x_ids, const float* __restrict__ atom_emb,
                      float* __restrict__ h, u32* __restrict__ hb, int* __restrict__ deg,
                      const float* __restrict__ W1, const float* __restrict__ W2,
                      u16* __restrict__ wt, const int* __restrict__ ei, int* __restrict__ gcur){
  int bid = blockIdx.x, tid = threadIdx.x;
  if (bid < 10000){                               // init: NN*64 items
    int idx = bid * 256 + tid;
    if (idx < NN) deg[idx] = 0;
    if (idx < 160) gcur[idx] = 0;
    if (idx < 64) hb[NN * 64 + idx] = 0xFF80FF80u;  // dummy node: both halves -inf
    int n = idx >> 6, d2 = idx & 63;
    float2 v = ((const float2*)(atom_emb + x_ids[n] * DD))[d2];
    ((float2*)h)[idx] = v;
    hb[idx] = pack2(v.x, v.y);
  } else if (bid < 10640){                        // wprep: 10*16384 items
    int idx = (bid - 10000) * 256 + tid;
    int m = idx >> 14, nk = idx & 16383;
    int n = nk >> 7, k = nk & 127;
    const float* src = (m < LL) ? (W1 + m * 16384) : (W2 + (m - LL) * 16384);
    wt[idx] = f2bf(src[k * DD + n]);
  } else {                                        // count: EE items
    int e = (bid - 10640) * 256 + tid;
    atomicAdd(&deg[ei[EE + e]], 1);
  }
}

// phase 1: per-block exclusive scan of PADDED degrees + block totals (40 blocks x 1024)
__global__ void k_scan1(const int* __restrict__ deg, int* __restrict__ rs, int* __restrict__ bsum){
  __shared__ int buf[1024];
  int tid = threadIdx.x;
  int i = blockIdx.x * 1024 + tid;
  int dv = (i < NN) ? deg[i] : 0;
  int v = (dv + 3) & ~3;                         // pad each segment to x4
  buf[tid] = v;
  __syncthreads();
  for (int off = 1; off < 1024; off <<= 1){
    int t = (tid >= off) ? buf[tid - off] : 0;
    __syncthreads();
    buf[tid] += t;
    __syncthreads();
  }
  int incl = buf[tid];
  if (i < NN) rs[i] = incl - v;
  if (tid == 1023) bsum[blockIdx.x] = incl;
}

// phase 2: add block offsets; rs[NN]=padded total
__global__ void k_scan2(int* __restrict__ rs, const int* __restrict__ bsum){
  __shared__ int s_off;
  int tid = threadIdx.x;
  if (tid < 64){
    int v = (tid < 40) ? bsum[tid] : 0;
    #pragma unroll
    for (int off = 1; off < 64; off <<= 1){
      int t = __shfl_up(v, off, 64);
      if (tid >= off) v += t;
    }
    int bx = (int)blockIdx.x;
    int ex = (bx == 0) ? 0 : __shfl(v, bx - 1, 64);
    if (tid == 0) s_off = ex;
    if (bx == 0 && tid == 39) rs[NN] = v;        // total padded edge count
  }
  __syncthreads();
  int i = blockIdx.x * 1024 + tid;
  if (i < NN) rs[i] += s_off;
}

// ---------------- binned CSR fill, pass 1: bucket edges by dst>>8 (append-style, coalesced) ----------------
__global__ __launch_bounds__(1024) void k_bin(const int* __restrict__ ei, const int* __restrict__ ea,
                                              int* __restrict__ gcur, u32* __restrict__ store){
  __shared__ int l_cnt[160];
  __shared__ int l_base[160];
  int tid = threadIdx.x;
  if (tid < 160) l_cnt[tid] = 0;
  __syncthreads();
  int e0 = blockIdx.x * 4096;                     // 157 blocks x 4096 >= EE
  u32 rec[4]; int rb[4], rr[4];
  #pragma unroll
  for (int j = 0; j < 4; ++j){
    int e = e0 + j * 1024 + tid;
    rb[j] = -1;
    if (e < EE){
      int dst = ei[EE + e];
      int b = dst >> 8;
      rb[j] = b;
      rr[j] = atomicAdd(&l_cnt[b], 1);            // local rank within (block,bucket)
      rec[j] = (u32)ei[e] | ((u32)ea[e] << 16) | ((u32)(dst & 255) << 18);
    }
  }
  __syncthreads();
  if (tid < 160) l_base[tid] = atomicAdd(&gcur[tid], l_cnt[tid]);
  __syncthreads();
  #pragma unroll
  for (int j = 0; j < 4; ++j)
    if (rb[j] >= 0)
      store[rb[j] * CAP + l_base[rb[j]] + rr[j]] = rec[j];
}

// ---------------- pass 2: block b owns bucket b; scatter into private col range + sentinel-fill ----------------
__global__ __launch_bounds__(1024) void k_place(const u32* __restrict__ store, const int* __restrict__ gcur,
                                                const int* __restrict__ rs, int* __restrict__ col){
  __shared__ int l_cur[256];
  int b = blockIdx.x, tid = threadIdx.x;
  int n0 = b << 8;
  if (tid < 256){
    int n = n0 + tid;
    l_cur[tid] = (n < NN) ? rs[n] : 0;
  }
  __syncthreads();
  int cnt = gcur[b];
  for (int r = tid; r < cnt; r += 1024){
    u32 rec = store[b * CAP + r];
    int dl = rec >> 18;
    int pos = atomicAdd(&l_cur[dl], 1);
    col[pos] = (int)((rec & 0xFFFFu) | (((rec >> 16) & 3u) << 20));
  }
  __syncthreads();
  if (tid < 256){                                 // pad gaps with sentinel (dummy node NN)
    int n = n0 + tid;
    if (n < NN){
      int e = l_cur[tid], end = rs[n + 1];
      for (; e < end; ++e) col[e] = NN;
    }
  }
}

// ---------------- gather: zb = bf16( (1+eps)*h + sum relu(hb[src]+bond[attr]) ); zeroes stats ----------------
__global__ __launch_bounds__(1024) void k_gather(
                         const float* __restrict__ h, const u32* __restrict__ hb,
                         const int* __restrict__ row_start, const int* __restrict__ col,
                         const float* __restrict__ bond_l, const float* __restrict__ eps_l,
                         u32* __restrict__ zb, float* __restrict__ stats_all){
  __shared__ float2 s_bond[4 * 64];
  __shared__ float s_eps;
  int tid = threadIdx.x;
  if (blockIdx.x < 2){                            // zero 4096 stat floats (2 sets x 8 slices x 256)
    stats_all[blockIdx.x * 2048 + tid] = 0.f;
    stats_all[blockIdx.x * 2048 + 1024 + tid] = 0.f;
  }
  if (tid < 256) s_bond[tid] = ((const float2*)bond_l)[tid];
  if (tid == 0) s_eps = 1.0f + eps_l[0];
  __syncthreads();
  int wid = tid >> 6, lane = tid & 63;
  int v = blockIdx.x * 16 + wid;                  // NN divisible by 16
  int sbeg = __builtin_amdgcn_readfirstlane(row_start[v]);      // multiple of 4
  int send = __builtin_amdgcn_readfirstlane(row_start[v + 1]);  // multiple of 4
  float a0 = 0.f, a1 = 0.f, b0 = 0.f, b1 = 0.f, c0 = 0.f, c1 = 0.f, d0 = 0.f, d1 = 0.f;
  int i = sbeg;
  for (; i + 8 <= send; i += 8){
    int4 ca = *(const int4*)(col + i);
    int4 cb = *(const int4*)(col + i + 4);
    u32 h0 = hb[(ca.x & 0xFFFFF) * 64 + lane];
    u32 h1 = hb[(ca.y & 0xFFFFF) * 64 + lane];
    u32 h2 = hb[(ca.z & 0xFFFFF) * 64 + lane];
    u32 h3 = hb[(ca.w & 0xFFFFF) * 64 + lane];
    u32 h4 = hb[(cb.x & 0xFFFFF) * 64 + lane];
    u32 h5 = hb[(cb.y & 0xFFFFF) * 64 + lane];
    u32 h6 = hb[(cb.z & 0xFFFFF) * 64 + lane];
    u32 h7 = hb[(cb.w & 0xFFFFF) * 64 + lane];
    float2 bb0 = s_bond[(ca.x >> 20) * 64 + lane];
    float2 bb1 = s_bond[(ca.y >> 20) * 64 + lane];
    float2 bb2 = s_bond[(ca.z >> 20) * 64 + lane];
    float2 bb3 = s_bond[(ca.w >> 20) * 64 + lane];
    float2 bb4 = s_bond[(cb.x >> 20) * 64 + lane];
    float2 bb5 = s_bond[(cb.y >> 20) * 64 + lane];
    float2 bb6 = s_bond[(cb.z >> 20) * 64 + lane];
    float2 bb7 = s_bond[(cb.w >> 20) * 64 + lane];
    a0 += fmaxf(bf2f(h0 & 0xFFFFu) + bb0.x, 0.f);
    a1 += fmaxf(bf2f(h0 >> 16)     + bb0.y, 0.f);
    b0 += fmaxf(bf2f(h1 & 0xFFFFu) + bb1.x, 0.f);
    b1 += fmaxf(bf2f(h1 >> 16)     + bb1.y, 0.f);
    c0 += fmaxf(bf2f(h2 & 0xFFFFu) + bb2.x, 0.f);
    c1 += fmaxf(bf2f(h2 >> 16)     + bb2.y, 0.f);
    d0 += fmaxf(bf2f(h3 & 0xFFFFu) + bb3.x, 0.f);
    d1 += fmaxf(bf2f(h3 >> 16)     + bb3.y, 0.f);
    a0 += fmaxf(bf2f(h4 & 0xFFFFu) + bb4.x, 0.f);
    a1 += fmaxf(bf2f(h4 >> 16)     + bb4.y, 0.f);
    b0 += fmaxf(bf2f(h5 & 0xFFFFu) + bb5.x, 0.f);
    b1 += fmaxf(bf2f(h5 >> 16)     + bb5.y, 0.f);
    c0 += fmaxf(bf2f(h6 & 0xFFFFu) + bb6.x, 0.f);
    c1 += fmaxf(bf2f(h6 >> 16)     + bb6.y, 0.f);
    d0 += fmaxf(bf2f(h7 & 0xFFFFu) + bb7.x, 0.f);
    d1 += fmaxf(bf2f(h7 >> 16)     + bb7.y, 0.f);
  }
  if (i < send){                                  // exactly 4 remain (padded)
    int4 ca = *(const int4*)(col + i);
    u32 h0 = hb[(ca.x & 0xFFFFF) * 64 + lane];
    u32 h1 = hb[(ca.y & 0xFFFFF) * 64 + lane];
    u32 h2 = hb[(ca.z & 0xFFFFF) * 64 + lane];
    u32 h3 = hb[(ca.w & 0xFFFFF) * 64 + lane];
    float2 bb0 = s_bond[(ca.x >> 20) * 64 + lane];
    float2 bb1 = s_bond[(ca.y >> 20) * 64 + lane];
    float2 bb2 = s_bond[(ca.z >> 20) * 64 + lane];
    float2 bb3 = s_bond[(ca.w >> 20) * 64 + lane];
    a0 += fmaxf(bf2f(h0 & 0xFFFFu) + bb0.x, 0.f);
    a1 += fmaxf(bf2f(h0 >> 16)     + bb0.y, 0.f);
    b0 += fmaxf(bf2f(h1 & 0xFFFFu) + bb1.x, 0.f);
    b1 += fmaxf(bf2f(h1 >> 16)     + bb1.y, 0.f);
    c0 += fmaxf(bf2f(h2 & 0xFFFFu) + bb2.x, 0.f);
    c1 += fmaxf(bf2f(h2 >> 16)     + bb2.y, 0.f);
    d0 += fmaxf(bf2f(h3 & 0xFFFFu) + bb3.x, 0.f);
    d1 += fmaxf(bf2f(h3 >> 16)     + bb3.y, 0.f);
  }
  float2 hv = ((const float2*)h)[v * 64 + lane];
  zb[v * 64 + lane] = pack2(s_eps * hv.x + a0 + b0 + c0 + d0,
                            s_eps * hv.y + a1 + b1 + c1 + d1);
}

// ---------------- MFMA GEMM: out(bf16) = A(bf16) @ W + b; 8-way sliced col stats; BN+ReLU in if BN ----------------
template<bool BN>
__global__ __launch_bounds__(256) void k_gemm(const u16* __restrict__ Asrc,
    const u16* __restrict__ Wt,               // bf16 Wt[n][k]
    const float* __restrict__ bias,
    const float* __restrict__ stats_in,       // 8 slices x [sum128|sq128]
    const float* __restrict__ g, const float* __restrict__ bt,
    u16* __restrict__ out, float* __restrict__ osum){
  __shared__ u16 sA[32 * 136];                // padded rows: 2-way bank aliasing (free)
  __shared__ float s_scale[DD], s_shift[DD];
  __shared__ float s_sum[DD], s_sq[DD];
  int tid = threadIdx.x;
  int row0 = blockIdx.x * 32;                 // 1250 blocks exact
  if (tid < DD){
    s_sum[tid] = 0.f; s_sq[tid] = 0.f;
    if (BN){
      float s = 0.f, q = 0.f;
      #pragma unroll
      for (int s8 = 0; s8 < 8; ++s8){
        s += stats_in[s8 * 256 + tid];
        q += stats_in[s8 * 256 + DD + tid];
      }
      float m   = s * (1.0f / NN);
      float var = q * (1.0f / NN) - m * m;
      float inv = rsqrtf(var + 1e-5f);
      float sc  = inv * g[tid];
      s_scale[tid] = sc;
      s_shift[tid] = bt[tid] - m * sc;
    }
  }
  __syncthreads();
  #pragma unroll
  for (int c0 = 0; c0 < 2; ++c0){
    int c = tid + c0 * 256;
    int row = c >> 4, off = (c & 15) * 8;
    uint4 v = *(const uint4*)(Asrc + (row0 + row) * DD + off);
    if (BN){
      u32 wv[4] = {v.x, v.y, v.z, v.w};
      union { u16 o[8]; uint4 v; } u;
      #pragma unroll
      for (int j = 0; j < 4; ++j){
        float y0 = bf2f(wv[j] & 0xFFFFu) * s_scale[off + 2*j]     + s_shift[off + 2*j];
        float y1 = bf2f(wv[j] >> 16)     * s_scale[off + 2*j + 1] + s_shift[off + 2*j + 1];
        u.o[2*j]     = f2bf(fmaxf(y0, 0.f));
        u.o[2*j + 1] = f2bf(fmaxf(y1, 0.f));
      }
      v = u.v;
    }
    *(uint4*)(sA + row * 136 + off) = v;
  }
  int w = tid >> 6, lane = tid & 63, lr = lane & 15, lk = lane >> 4;
  bf8 bfr[2][4];
  #pragma unroll
  for (int nt = 0; nt < 2; ++nt){
    int n = w * 32 + nt * 16 + lr;
    #pragma unroll
    for (int kt = 0; kt < 4; ++kt)
      bfr[nt][kt] = *(const bf8*)(Wt + n * DD + kt * 32 + lk * 8);
  }
  __syncthreads();
  f4 acc[2][2];
  #pragma unroll
  for (int mt = 0; mt < 2; ++mt)
    #pragma unroll
    for (int nt = 0; nt < 2; ++nt) acc[mt][nt] = (f4){0.f, 0.f, 0.f, 0.f};
  #pragma unroll
  for (int kt = 0; kt < 4; ++kt){
    bf8 a0 = *(const bf8*)(sA + lr * 136        + kt * 32 + lk * 8);
    bf8 a1 = *(const bf8*)(sA + (16 + lr) * 136 + kt * 32 + lk * 8);
    acc[0][0] = __builtin_amdgcn_mfma_f32_16x16x32_bf16(a0, bfr[0][kt], acc[0][0], 0, 0, 0);
    acc[0][1] = __builtin_amdgcn_mfma_f32_16x16x32_bf16(a0, bfr[1][kt], acc[0][1], 0, 0, 0);
    acc[1][0] = __builtin_amdgcn_mfma_f32_16x16x32_bf16(a1, bfr[0][kt], acc[1][0], 0, 0, 0);
    acc[1][1] = __builtin_amdgcn_mfma_f32_16x16x32_bf16(a1, bfr[1][kt], acc[1][1], 0, 0, 0);
  }
  // epilogue: C/D layout col=lane&15, row=(lane>>4)*4+reg; stats from bf16-rounded values
  #pragma unroll
  for (int nt = 0; nt < 2; ++nt){
    int colg = w * 32 + nt * 16 + lr;
    float bv = bias[colg];
    float cs = 0.f, cq = 0.f;
    #pragma unroll
    for (int mt = 0; mt < 2; ++mt){
      #pragma unroll
      for (int r = 0; r < 4; ++r){
        u16 yb = f2bf(acc[mt][nt][r] + bv);
        float yr = bf2f(yb);
        out[(row0 + mt * 16 + lk * 4 + r) * DD + colg] = yb;
        cs += yr; cq += yr * yr;
      }
    }
    atomicAdd(&s_sum[colg], cs);
    atomicAdd(&s_sq[colg], cq);
  }
  __syncthreads();
  float* slice = osum + (blockIdx.x & 7) * 256;   // 8-way contention split
  if (tid < DD){
    atomicAdd(&slice[tid],      s_sum[tid]);
    atomicAdd(&slice[DD + tid], s_sq[tid]);
  }
}

// ---------------- BN2 (+ReLU except last) + residual; update fp32 h and bf16 mirror ----------------
__global__ void k_final(const u32* __restrict__ zf, const float* __restrict__ stats2,
                        const float* __restrict__ gl, const float* __restrict__ bl,
                        float* __restrict__ h, u32* __restrict__ hb, int do_relu){
  __shared__ float s_scale[DD], s_shift[DD];
  int tid = threadIdx.x;
  if (tid < DD){
    float s = 0.f, q = 0.f;
    #pragma unroll
    for (int s8 = 0; s8 < 8; ++s8){
      s += stats2[s8 * 256 + tid];
      q += stats2[s8 * 256 + DD + tid];
    }
    float m   = s * (1.0f / NN);
    float var = q * (1.0f / NN) - m * m;
    float inv = rsqrtf(var + 1e-5f);
    float sc  = inv * gl[tid];
    s_scale[tid] = sc;
    s_shift[tid] = bl[tid] - m * sc;
  }
  __syncthreads();
  int idx = blockIdx.x * 256 + tid;           // NN*64
  int j0 = (idx & 63) * 2;
  u32 zz = zf[idx];
  float val0 = bf2f(zz & 0xFFFFu) * s_scale[j0]     + s_shift[j0];
  float val1 = bf2f(zz >> 16)     * s_scale[j0 + 1] + s_shift[j0 + 1];
  if (do_relu){ val0 = fmaxf(val0, 0.f); val1 = fmaxf(val1, 0.f); }
  float2 hv = ((float2*)h)[idx];
  hv.x += val0; hv.y += val1;
  ((float2*)h)[idx] = hv;
  hb[idx] = pack2(hv.x, hv.y);
}

extern "C" void kernel_launch(void* const* d_in, const int* in_sizes, int n_in,
                              void* d_out, int out_size, void* d_ws, size_t ws_size,
                              hipStream_t stream) {
  const int*   x_ids      = (const int*)d_in[0];
  const int*   edge_index = (const int*)d_in[1];
  const int*   edge_attr  = (const int*)d_in[2];
  const float* atom_emb   = (const float*)d_in[3];
  const float* bond_emb   = (const float*)d_in[4];
  const float* W1    = (const float*)d_in[5];
  const float* b1    = (const float*)d_in[6];
  const float* g1    = (const float*)d_in[7];
  const float* bt1   = (const float*)d_in[8];
  const float* W2    = (const float*)d_in[9];
  const float* b2    = (const float*)d_in[10];
  const float* eps   = (const float*)d_in[11];
  const float* g_out = (const float*)d_in[12];
  const float* b_out = (const float*)d_in[13];

  float* h   = (float*)d_out;                 // NN*DD fp32 running node state
  u32*   zb  = (u32*)d_ws;                    // NN*64: bf16 gather out (loop) / bin store (prologue)
  u32*   z2b = zb  + NN * 64;                 // NN*64: bf16 gemm1 out
  u32*   zAb = z2b + NN * 64;                 // NN*64: bf16 gemm2 out
  u32*   hb  = zAb + NN * 64;                 // (NN+1)*64: bf16 mirror of h + sentinel row
  u16*   wt  = (u16*)(hb + (NN + 1) * 64);    // 10*16384 bf16 transposed weights
  float* stats = (float*)(wt + 10 * 16384);   // 4096: 2 sets x 8 slices x [sum128|sq128]
  int* row_start = (int*)(stats + 4096);      // NN+4
  int* deg       = row_start + NN + 4;
  int* col       = deg + NN;                  // EE + 3*NN (padded)
  int* bsum      = col + EE + 3 * NN;         // 40
  int* gcur      = bsum + 64;                 // 160 bucket cursors

  u32* store = zb;                            // NB*CAP u32 records (5.1 MB <= 10.2 MB zb; dead before loop)

  k_pre  <<<13140, 256, 0, stream>>>(x_ids, atom_emb, h, hb, deg, W1, W2, wt, edge_index, gcur);
  k_scan1<<<40, 1024, 0, stream>>>(deg, row_start, bsum);
  k_scan2<<<40, 1024, 0, stream>>>(row_start, bsum);
  k_bin  <<<NB, 1024, 0, stream>>>(edge_index, edge_attr, gcur, store);
  k_place<<<NB, 1024, 0, stream>>>(store, gcur, row_start, col);

  for (int l = 0; l < LL; ++l){
    k_gather<<<NN / 16, 1024, 0, stream>>>(h, hb, row_start, col,
                                           bond_emb + l * 4 * DD, eps + l, zb, stats);
    k_gemm<false><<<NN / 32, 256, 0, stream>>>((const u16*)zb, wt + l * 16384, b1 + l * DD,
                                               nullptr, nullptr, nullptr, (u16*)z2b, stats);
    k_gemm<true> <<<NN / 32, 256, 0, stream>>>((const u16*)z2b, wt + (LL + l) * 16384, b2 + l * DD,
                                               stats, g1 + l * DD, bt1 + l * DD, (u16*)zAb, stats + 2048);
    k_final<<<NN * 64 / 256, 256, 0, stream>>>(zAb, stats + 2048,
                                               g_out + l * DD, b_out + l * DD,
                                               h, hb, (l < LL - 1) ? 1 : 0);
  }
}

// Round 8
// 446.251 us; speedup vs baseline: 2.7628x; 1.0895x over previous
//
#include <hip/hip_runtime.h>

#define NN 40000
#define EE 640000
#define DD 128
#define LL 5
#define NB 157          // buckets of 256 dst nodes
#define CAP 8192        // slots per bucket (mean 4096, sigma ~64)

typedef unsigned short u16;
typedef unsigned int   u32;
typedef __attribute__((ext_vector_type(8))) short bf8;   // 8 bf16 = 4 VGPRs
typedef __attribute__((ext_vector_type(4))) float f4;

__device__ __forceinline__ float bf2f(u32 u){ union{u32 i; float f;} x; x.i = u << 16; return x.f; }
__device__ __forceinline__ u16 f2bf(float f){
  union{float f; u32 i;} x; x.f = f;
  u32 r = x.i + 0x7FFFu + ((x.i >> 16) & 1u);
  return (u16)(r >> 16);
}
__device__ __forceinline__ u32 pack2(float a, float b){ return (u32)f2bf(a) | ((u32)f2bf(b) << 16); }

// ---------------- merged prologue: init h/hb/deg/gcur/sentinel | wprep | count ----------------
__global__ void k_pre(const int* __restrict__ x_ids, const float* __restrict__ atom_emb,
                      float* __restrict__ h, u32* __restrict__ hb, int* __restrict__ deg,
                      const float* __restrict__ W1, const float* __restrict__ W2,
                      u16* __restrict__ wt, const int* __restrict__ ei, int* __restrict__ gcur){
  int bid = blockIdx.x, tid = threadIdx.x;
  if (bid < 10000){                               // init: NN*64 items
    int idx = bid * 256 + tid;
    if (idx < NN) deg[idx] = 0;
    if (idx < 160) gcur[idx] = 0;
    if (idx < 64) hb[NN * 64 + idx] = 0xFF80FF80u;  // dummy node: both halves -inf
    int n = idx >> 6, d2 = idx & 63;
    float2 v = ((const float2*)(atom_emb + x_ids[n] * DD))[d2];
    ((float2*)h)[idx] = v;
    hb[idx] = pack2(v.x, v.y);
  } else if (bid < 10640){                        // wprep: 10*16384 items
    int idx = (bid - 10000) * 256 + tid;
    int m = idx >> 14, nk = idx & 16383;
    int n = nk >> 7, k = nk & 127;
    const float* src = (m < LL) ? (W1 + m * 16384) : (W2 + (m - LL) * 16384);
    wt[idx] = f2bf(src[k * DD + n]);
  } else {                                        // count: EE items
    int e = (bid - 10640) * 256 + tid;
    atomicAdd(&deg[ei[EE + e]], 1);
  }
}

// phase 1: per-block exclusive scan of PADDED degrees + block totals (40 blocks x 1024)
__global__ void k_scan1(const int* __restrict__ deg, int* __restrict__ rs, int* __restrict__ bsum){
  __shared__ int buf[1024];
  int tid = threadIdx.x;
  int i = blockIdx.x * 1024 + tid;
  int dv = (i < NN) ? deg[i] : 0;
  int v = (dv + 3) & ~3;                         // pad each segment to x4
  buf[tid] = v;
  __syncthreads();
  for (int off = 1; off < 1024; off <<= 1){
    int t = (tid >= off) ? buf[tid - off] : 0;
    __syncthreads();
    buf[tid] += t;
    __syncthreads();
  }
  int incl = buf[tid];
  if (i < NN) rs[i] = incl - v;
  if (tid == 1023) bsum[blockIdx.x] = incl;
}

// phase 2: add block offsets; rs[NN]=padded total
__global__ void k_scan2(int* __restrict__ rs, const int* __restrict__ bsum){
  __shared__ int s_off;
  int tid = threadIdx.x;
  if (tid < 64){
    int v = (tid < 40) ? bsum[tid] : 0;
    #pragma unroll
    for (int off = 1; off < 64; off <<= 1){
      int t = __shfl_up(v, off, 64);
      if (tid >= off) v += t;
    }
    int bx = (int)blockIdx.x;
    int ex = (bx == 0) ? 0 : __shfl(v, bx - 1, 64);
    if (tid == 0) s_off = ex;
    if (bx == 0 && tid == 39) rs[NN] = v;        // total padded edge count
  }
  __syncthreads();
  int i = blockIdx.x * 1024 + tid;
  if (i < NN) rs[i] += s_off;
}

// ---------------- binned CSR fill, pass 1: bucket edges by dst>>8 (append-style, coalesced) ----------------
__global__ __launch_bounds__(1024) void k_bin(const int* __restrict__ ei, const int* __restrict__ ea,
                                              int* __restrict__ gcur, u32* __restrict__ store){
  __shared__ int l_cnt[160];
  __shared__ int l_base[160];
  int tid = threadIdx.x;
  if (tid < 160) l_cnt[tid] = 0;
  __syncthreads();
  int e0 = blockIdx.x * 4096;                     // 157 blocks x 4096 >= EE
  u32 rec[4]; int rb[4], rr[4];
  #pragma unroll
  for (int j = 0; j < 4; ++j){
    int e = e0 + j * 1024 + tid;
    rb[j] = -1;
    if (e < EE){
      int dst = ei[EE + e];
      int b = dst >> 8;
      rb[j] = b;
      rr[j] = atomicAdd(&l_cnt[b], 1);            // local rank within (block,bucket)
      rec[j] = (u32)ei[e] | ((u32)ea[e] << 16) | ((u32)(dst & 255) << 18);
    }
  }
  __syncthreads();
  if (tid < 160) l_base[tid] = atomicAdd(&gcur[tid], l_cnt[tid]);
  __syncthreads();
  #pragma unroll
  for (int j = 0; j < 4; ++j)
    if (rb[j] >= 0)
      store[rb[j] * CAP + l_base[rb[j]] + rr[j]] = rec[j];
}

// ---------------- pass 2: block b owns bucket b; scatter into private col range + sentinel-fill ----------------
// block 0 also zeroes stats1 (for layer 0's fused gather+gemm1)
__global__ __launch_bounds__(1024) void k_place(const u32* __restrict__ store, const int* __restrict__ gcur,
                                                const int* __restrict__ rs, int* __restrict__ col,
                                                float* __restrict__ stats1){
  __shared__ int l_cur[256];
  int b = blockIdx.x, tid = threadIdx.x;
  if (b == 0){ stats1[tid] = 0.f; stats1[1024 + tid] = 0.f; }
  int n0 = b << 8;
  if (tid < 256){
    int n = n0 + tid;
    l_cur[tid] = (n < NN) ? rs[n] : 0;
  }
  __syncthreads();
  int cnt = gcur[b];
  for (int r = tid; r < cnt; r += 1024){
    u32 rec = store[b * CAP + r];
    int dl = rec >> 18;
    int pos = atomicAdd(&l_cur[dl], 1);
    col[pos] = (int)((rec & 0xFFFFu) | (((rec >> 16) & 3u) << 20));
  }
  __syncthreads();
  if (tid < 256){                                 // pad gaps with sentinel (dummy node NN)
    int n = n0 + tid;
    if (n < NN){
      int e = l_cur[tid], end = rs[n + 1];
      for (; e < end; ++e) col[e] = NN;
    }
  }
}

// ---------------- FUSED gather + GEMM1: z=(1+eps)h+sum relu(hb[src]+bond) -> LDS -> MFMA @W1+b1 ----------------
// 1250 blocks x 256 thr; 4 waves x 8 nodes gather into sA, then 32x128 MFMA tile.
// Writes z2b (bf16) + 8-way sliced stats1. Block 0 zeroes stats2 (consumed later by gemm2/final chain).
__global__ __launch_bounds__(256, 4) void k_gg(
    const float* __restrict__ h, const u32* __restrict__ hb,
    const int* __restrict__ row_start, const int* __restrict__ col,
    const float* __restrict__ bond_l, const float* __restrict__ eps_l,
    const u16* __restrict__ Wt, const float* __restrict__ bias,
    u16* __restrict__ out, float* __restrict__ osum, float* __restrict__ stats2){
  __shared__ u16 sA[32 * 136];
  __shared__ float2 s_bond[4 * 64];
  __shared__ float s_eps;
  __shared__ float s_sum[DD], s_sq[DD];
  int tid = threadIdx.x;
  if (blockIdx.x == 0){                           // zero stats2 for this layer (race-free: nobody
    #pragma unroll                                // touches stats2 until next dispatch)
    for (int j = 0; j < 8; ++j) stats2[j * 256 + tid] = 0.f;
  }
  if (tid < 256) s_bond[tid] = ((const float2*)bond_l)[tid];
  if (tid == 0) s_eps = 1.0f + eps_l[0];
  if (tid < DD){ s_sum[tid] = 0.f; s_sq[tid] = 0.f; }
  __syncthreads();
  int w = tid >> 6, lane = tid & 63;
  // ---- gather phase: wave w handles local rows w*8 .. w*8+7 ----
  for (int j = 0; j < 8; ++j){
    int v = blockIdx.x * 32 + w * 8 + j;
    int sbeg = __builtin_amdgcn_readfirstlane(row_start[v]);      // multiple of 4
    int send = __builtin_amdgcn_readfirstlane(row_start[v + 1]);  // multiple of 4
    float a0 = 0.f, a1 = 0.f, b0 = 0.f, b1 = 0.f, c0 = 0.f, c1 = 0.f, d0 = 0.f, d1 = 0.f;
    int i = sbeg;
    for (; i + 8 <= send; i += 8){
      int4 ca = *(const int4*)(col + i);
      int4 cb = *(const int4*)(col + i + 4);
      u32 h0 = hb[(ca.x & 0xFFFFF) * 64 + lane];
      u32 h1 = hb[(ca.y & 0xFFFFF) * 64 + lane];
      u32 h2 = hb[(ca.z & 0xFFFFF) * 64 + lane];
      u32 h3 = hb[(ca.w & 0xFFFFF) * 64 + lane];
      u32 h4 = hb[(cb.x & 0xFFFFF) * 64 + lane];
      u32 h5 = hb[(cb.y & 0xFFFFF) * 64 + lane];
      u32 h6 = hb[(cb.z & 0xFFFFF) * 64 + lane];
      u32 h7 = hb[(cb.w & 0xFFFFF) * 64 + lane];
      float2 bb0 = s_bond[(ca.x >> 20) * 64 + lane];
      float2 bb1 = s_bond[(ca.y >> 20) * 64 + lane];
      float2 bb2 = s_bond[(ca.z >> 20) * 64 + lane];
      float2 bb3 = s_bond[(ca.w >> 20) * 64 + lane];
      float2 bb4 = s_bond[(cb.x >> 20) * 64 + lane];
      float2 bb5 = s_bond[(cb.y >> 20) * 64 + lane];
      float2 bb6 = s_bond[(cb.z >> 20) * 64 + lane];
      float2 bb7 = s_bond[(cb.w >> 20) * 64 + lane];
      a0 += fmaxf(bf2f(h0 & 0xFFFFu) + bb0.x, 0.f);
      a1 += fmaxf(bf2f(h0 >> 16)     + bb0.y, 0.f);
      b0 += fmaxf(bf2f(h1 & 0xFFFFu) + bb1.x, 0.f);
      b1 += fmaxf(bf2f(h1 >> 16)     + bb1.y, 0.f);
      c0 += fmaxf(bf2f(h2 & 0xFFFFu) + bb2.x, 0.f);
      c1 += fmaxf(bf2f(h2 >> 16)     + bb2.y, 0.f);
      d0 += fmaxf(bf2f(h3 & 0xFFFFu) + bb3.x, 0.f);
      d1 += fmaxf(bf2f(h3 >> 16)     + bb3.y, 0.f);
      a0 += fmaxf(bf2f(h4 & 0xFFFFu) + bb4.x, 0.f);
      a1 += fmaxf(bf2f(h4 >> 16)     + bb4.y, 0.f);
      b0 += fmaxf(bf2f(h5 & 0xFFFFu) + bb5.x, 0.f);
      b1 += fmaxf(bf2f(h5 >> 16)     + bb5.y, 0.f);
      c0 += fmaxf(bf2f(h6 & 0xFFFFu) + bb6.x, 0.f);
      c1 += fmaxf(bf2f(h6 >> 16)     + bb6.y, 0.f);
      d0 += fmaxf(bf2f(h7 & 0xFFFFu) + bb7.x, 0.f);
      d1 += fmaxf(bf2f(h7 >> 16)     + bb7.y, 0.f);
    }
    if (i < send){                                // exactly 4 remain (padded)
      int4 ca = *(const int4*)(col + i);
      u32 h0 = hb[(ca.x & 0xFFFFF) * 64 + lane];
      u32 h1 = hb[(ca.y & 0xFFFFF) * 64 + lane];
      u32 h2 = hb[(ca.z & 0xFFFFF) * 64 + lane];
      u32 h3 = hb[(ca.w & 0xFFFFF) * 64 + lane];
      float2 bb0 = s_bond[(ca.x >> 20) * 64 + lane];
      float2 bb1 = s_bond[(ca.y >> 20) * 64 + lane];
      float2 bb2 = s_bond[(ca.z >> 20) * 64 + lane];
      float2 bb3 = s_bond[(ca.w >> 20) * 64 + lane];
      a0 += fmaxf(bf2f(h0 & 0xFFFFu) + bb0.x, 0.f);
      a1 += fmaxf(bf2f(h0 >> 16)     + bb0.y, 0.f);
      b0 += fmaxf(bf2f(h1 & 0xFFFFu) + bb1.x, 0.f);
      b1 += fmaxf(bf2f(h1 >> 16)     + bb1.y, 0.f);
      c0 += fmaxf(bf2f(h2 & 0xFFFFu) + bb2.x, 0.f);
      c1 += fmaxf(bf2f(h2 >> 16)     + bb2.y, 0.f);
      d0 += fmaxf(bf2f(h3 & 0xFFFFu) + bb3.x, 0.f);
      d1 += fmaxf(bf2f(h3 >> 16)     + bb3.y, 0.f);
    }
    float2 hv = ((const float2*)h)[v * 64 + lane];
    u32 zp = pack2(s_eps * hv.x + a0 + b0 + c0 + d0,
                   s_eps * hv.y + a1 + b1 + c1 + d1);
    *(u32*)(sA + (w * 8 + j) * 136 + lane * 2) = zp;
  }
  // ---- B fragments (L2-resident Wt) ----
  int lr = lane & 15, lk = lane >> 4;
  bf8 bfr[2][4];
  #pragma unroll
  for (int nt = 0; nt < 2; ++nt){
    int n = w * 32 + nt * 16 + lr;
    #pragma unroll
    for (int kt = 0; kt < 4; ++kt)
      bfr[nt][kt] = *(const bf8*)(Wt + n * DD + kt * 32 + lk * 8);
  }
  __syncthreads();
  // ---- MFMA phase ----
  f4 acc[2][2];
  #pragma unroll
  for (int mt = 0; mt < 2; ++mt)
    #pragma unroll
    for (int nt = 0; nt < 2; ++nt) acc[mt][nt] = (f4){0.f, 0.f, 0.f, 0.f};
  #pragma unroll
  for (int kt = 0; kt < 4; ++kt){
    bf8 a0 = *(const bf8*)(sA + lr * 136        + kt * 32 + lk * 8);
    bf8 a1 = *(const bf8*)(sA + (16 + lr) * 136 + kt * 32 + lk * 8);
    acc[0][0] = __builtin_amdgcn_mfma_f32_16x16x32_bf16(a0, bfr[0][kt], acc[0][0], 0, 0, 0);
    acc[0][1] = __builtin_amdgcn_mfma_f32_16x16x32_bf16(a0, bfr[1][kt], acc[0][1], 0, 0, 0);
    acc[1][0] = __builtin_amdgcn_mfma_f32_16x16x32_bf16(a1, bfr[0][kt], acc[1][0], 0, 0, 0);
    acc[1][1] = __builtin_amdgcn_mfma_f32_16x16x32_bf16(a1, bfr[1][kt], acc[1][1], 0, 0, 0);
  }
  int row0 = blockIdx.x * 32;
  #pragma unroll
  for (int nt = 0; nt < 2; ++nt){
    int colg = w * 32 + nt * 16 + lr;
    float bv = bias[colg];
    float cs = 0.f, cq = 0.f;
    #pragma unroll
    for (int mt = 0; mt < 2; ++mt){
      #pragma unroll
      for (int r = 0; r < 4; ++r){
        u16 yb = f2bf(acc[mt][nt][r] + bv);
        float yr = bf2f(yb);
        out[(row0 + mt * 16 + lk * 4 + r) * DD + colg] = yb;
        cs += yr; cq += yr * yr;
      }
    }
    atomicAdd(&s_sum[colg], cs);
    atomicAdd(&s_sq[colg], cq);
  }
  __syncthreads();
  float* slice = osum + (blockIdx.x & 7) * 256;
  if (tid < DD){
    atomicAdd(&slice[tid],      s_sum[tid]);
    atomicAdd(&slice[DD + tid], s_sq[tid]);
  }
}

// ---------------- GEMM2: BN1+ReLU on input, MFMA @W2+b2, bf16 out + sliced stats2 ----------------
__global__ __launch_bounds__(256) void k_gemm2(const u16* __restrict__ Asrc,
    const u16* __restrict__ Wt, const float* __restrict__ bias,
    const float* __restrict__ stats_in,       // 8 slices x [sum128|sq128]
    const float* __restrict__ g, const float* __restrict__ bt,
    u16* __restrict__ out, float* __restrict__ osum){
  __shared__ u16 sA[32 * 136];
  __shared__ float s_scale[DD], s_shift[DD];
  __shared__ float s_sum[DD], s_sq[DD];
  int tid = threadIdx.x;
  int row0 = blockIdx.x * 32;
  if (tid < DD){
    s_sum[tid] = 0.f; s_sq[tid] = 0.f;
    float s = 0.f, q = 0.f;
    #pragma unroll
    for (int s8 = 0; s8 < 8; ++s8){
      s += stats_in[s8 * 256 + tid];
      q += stats_in[s8 * 256 + DD + tid];
    }
    float m   = s * (1.0f / NN);
    float var = q * (1.0f / NN) - m * m;
    float inv = rsqrtf(var + 1e-5f);
    float sc  = inv * g[tid];
    s_scale[tid] = sc;
    s_shift[tid] = bt[tid] - m * sc;
  }
  __syncthreads();
  #pragma unroll
  for (int c0 = 0; c0 < 2; ++c0){
    int c = tid + c0 * 256;
    int row = c >> 4, off = (c & 15) * 8;
    uint4 v = *(const uint4*)(Asrc + (row0 + row) * DD + off);
    u32 wv[4] = {v.x, v.y, v.z, v.w};
    union { u16 o[8]; uint4 v; } u;
    #pragma unroll
    for (int j = 0; j < 4; ++j){
      float y0 = bf2f(wv[j] & 0xFFFFu) * s_scale[off + 2*j]     + s_shift[off + 2*j];
      float y1 = bf2f(wv[j] >> 16)     * s_scale[off + 2*j + 1] + s_shift[off + 2*j + 1];
      u.o[2*j]     = f2bf(fmaxf(y0, 0.f));
      u.o[2*j + 1] = f2bf(fmaxf(y1, 0.f));
    }
    *(uint4*)(sA + row * 136 + off) = u.v;
  }
  int w = tid >> 6, lane = tid & 63, lr = lane & 15, lk = lane >> 4;
  bf8 bfr[2][4];
  #pragma unroll
  for (int nt = 0; nt < 2; ++nt){
    int n = w * 32 + nt * 16 + lr;
    #pragma unroll
    for (int kt = 0; kt < 4; ++kt)
      bfr[nt][kt] = *(const bf8*)(Wt + n * DD + kt * 32 + lk * 8);
  }
  __syncthreads();
  f4 acc[2][2];
  #pragma unroll
  for (int mt = 0; mt < 2; ++mt)
    #pragma unroll
    for (int nt = 0; nt < 2; ++nt) acc[mt][nt] = (f4){0.f, 0.f, 0.f, 0.f};
  #pragma unroll
  for (int kt = 0; kt < 4; ++kt){
    bf8 a0 = *(const bf8*)(sA + lr * 136        + kt * 32 + lk * 8);
    bf8 a1 = *(const bf8*)(sA + (16 + lr) * 136 + kt * 32 + lk * 8);
    acc[0][0] = __builtin_amdgcn_mfma_f32_16x16x32_bf16(a0, bfr[0][kt], acc[0][0], 0, 0, 0);
    acc[0][1] = __builtin_amdgcn_mfma_f32_16x16x32_bf16(a0, bfr[1][kt], acc[0][1], 0, 0, 0);
    acc[1][0] = __builtin_amdgcn_mfma_f32_16x16x32_bf16(a1, bfr[0][kt], acc[1][0], 0, 0, 0);
    acc[1][1] = __builtin_amdgcn_mfma_f32_16x16x32_bf16(a1, bfr[1][kt], acc[1][1], 0, 0, 0);
  }
  #pragma unroll
  for (int nt = 0; nt < 2; ++nt){
    int colg = w * 32 + nt * 16 + lr;
    float bv = bias[colg];
    float cs = 0.f, cq = 0.f;
    #pragma unroll
    for (int mt = 0; mt < 2; ++mt){
      #pragma unroll
      for (int r = 0; r < 4; ++r){
        u16 yb = f2bf(acc[mt][nt][r] + bv);
        float yr = bf2f(yb);
        out[(row0 + mt * 16 + lk * 4 + r) * DD + colg] = yb;
        cs += yr; cq += yr * yr;
      }
    }
    atomicAdd(&s_sum[colg], cs);
    atomicAdd(&s_sq[colg], cq);
  }
  __syncthreads();
  float* slice = osum + (blockIdx.x & 7) * 256;
  if (tid < DD){
    atomicAdd(&slice[tid],      s_sum[tid]);
    atomicAdd(&slice[DD + tid], s_sq[tid]);
  }
}

// ---------------- BN2 (+ReLU except last) + residual; 4 feats/thread; block 0 zeroes stats1 ----------------
__global__ void k_final(const u32* __restrict__ zf, const float* __restrict__ stats2,
                        const float* __restrict__ gl, const float* __restrict__ bl,
                        float* __restrict__ h, u32* __restrict__ hb, int do_relu,
                        float* __restrict__ stats1){
  __shared__ float s_scale[DD], s_shift[DD];
  int tid = threadIdx.x;
  if (blockIdx.x == 0){                           // zero stats1 for next layer's k_gg
    #pragma unroll
    for (int j = 0; j < 8; ++j) stats1[j * 256 + tid] = 0.f;
  }
  if (tid < DD){
    float s = 0.f, q = 0.f;
    #pragma unroll
    for (int s8 = 0; s8 < 8; ++s8){
      s += stats2[s8 * 256 + tid];
      q += stats2[s8 * 256 + DD + tid];
    }
    float m   = s * (1.0f / NN);
    float var = q * (1.0f / NN) - m * m;
    float inv = rsqrtf(var + 1e-5f);
    float sc  = inv * gl[tid];
    s_scale[tid] = sc;
    s_shift[tid] = bl[tid] - m * sc;
  }
  __syncthreads();
  int idx = blockIdx.x * 256 + tid;           // NN*32 items, 4 feats each
  int j0 = (idx & 31) * 4;
  uint2 zz = ((const uint2*)zf)[idx];
  float val0 = bf2f(zz.x & 0xFFFFu) * s_scale[j0]     + s_shift[j0];
  float val1 = bf2f(zz.x >> 16)     * s_scale[j0 + 1] + s_shift[j0 + 1];
  float val2 = bf2f(zz.y & 0xFFFFu) * s_scale[j0 + 2] + s_shift[j0 + 2];
  float val3 = bf2f(zz.y >> 16)     * s_scale[j0 + 3] + s_shift[j0 + 3];
  if (do_relu){
    val0 = fmaxf(val0, 0.f); val1 = fmaxf(val1, 0.f);
    val2 = fmaxf(val2, 0.f); val3 = fmaxf(val3, 0.f);
  }
  float4 hv = ((float4*)h)[idx];
  hv.x += val0; hv.y += val1; hv.z += val2; hv.w += val3;
  ((float4*)h)[idx] = hv;
  uint2 hp; hp.x = pack2(hv.x, hv.y); hp.y = pack2(hv.z, hv.w);
  ((uint2*)hb)[idx] = hp;
}

extern "C" void kernel_launch(void* const* d_in, const int* in_sizes, int n_in,
                              void* d_out, int out_size, void* d_ws, size_t ws_size,
                              hipStream_t stream) {
  const int*   x_ids      = (const int*)d_in[0];
  const int*   edge_index = (const int*)d_in[1];
  const int*   edge_attr  = (const int*)d_in[2];
  const float* atom_emb   = (const float*)d_in[3];
  const float* bond_emb   = (const float*)d_in[4];
  const float* W1    = (const float*)d_in[5];
  const float* b1    = (const float*)d_in[6];
  const float* g1    = (const float*)d_in[7];
  const float* bt1   = (const float*)d_in[8];
  const float* W2    = (const float*)d_in[9];
  const float* b2    = (const float*)d_in[10];
  const float* eps   = (const float*)d_in[11];
  const float* g_out = (const float*)d_in[12];
  const float* b_out = (const float*)d_in[13];

  float* h   = (float*)d_out;                 // NN*DD fp32 running node state
  u32*   zb  = (u32*)d_ws;                    // prologue: bin store; loop: unused
  u32*   z2b = zb  + NN * 64;                 // NN*64: bf16 gemm1 out
  u32*   zAb = z2b + NN * 64;                 // NN*64: bf16 gemm2 out
  u32*   hb  = zAb + NN * 64;                 // (NN+1)*64: bf16 mirror of h + sentinel row
  u16*   wt  = (u16*)(hb + (NN + 1) * 64);    // 10*16384 bf16 transposed weights
  float* stats = (float*)(wt + 10 * 16384);   // 4096: stats1[0..2047] | stats2[2048..4095]
  int* row_start = (int*)(stats + 4096);      // NN+4
  int* deg       = row_start + NN + 4;
  int* col       = deg + NN;                  // EE + 3*NN (padded)
  int* bsum      = col + EE + 3 * NN;         // 40
  int* gcur      = bsum + 64;                 // 160 bucket cursors

  u32* store = zb;                            // NB*CAP u32 records (5.1 MB; dead before loop)

  k_pre  <<<13140, 256, 0, stream>>>(x_ids, atom_emb, h, hb, deg, W1, W2, wt, edge_index, gcur);
  k_scan1<<<40, 1024, 0, stream>>>(deg, row_start, bsum);
  k_scan2<<<40, 1024, 0, stream>>>(row_start, bsum);
  k_bin  <<<NB, 1024, 0, stream>>>(edge_index, edge_attr, gcur, store);
  k_place<<<NB, 1024, 0, stream>>>(store, gcur, row_start, col, stats);

  for (int l = 0; l < LL; ++l){
    k_gg   <<<NN / 32, 256, 0, stream>>>(h, hb, row_start, col,
                                         bond_emb + l * 4 * DD, eps + l,
                                         wt + l * 16384, b1 + l * DD,
                                         (u16*)z2b, stats, stats + 2048);
    k_gemm2<<<NN / 32, 256, 0, stream>>>((const u16*)z2b, wt + (LL + l) * 16384, b2 + l * DD,
                                         stats, g1 + l * DD, bt1 + l * DD,
                                         (u16*)zAb, stats + 2048);
    k_final<<<NN * 32 / 256, 256, 0, stream>>>(zAb, stats + 2048,
                                               g_out + l * DD, b_out + l * DD,
                                               h, hb, (l < LL - 1) ? 1 : 0, stats);
  }
}